// Round 4
// baseline (1017.047 us; speedup 1.0000x reference)
//
#include <hip/hip_runtime.h>
#include <hip/hip_bf16.h>

// ---------------------------------------------------------------- constants
// E=128 GH=8 GD=16 GL=3 | SH=4 SD=32 SL=4 | N=32 GC=64 GS=16 DEG=64 BMOL=16
// M_conf=4096 M_scaf=1024 M_tot=5120. All float tensors are fp32 per reference.

// ---------------------------------------------------------------- zero fill
__global__ __launch_bounds__(256) void zero_k(float* __restrict__ p, int n)
{
  int i = blockIdx.x * 256 + threadIdx.x;
  if (i < n) p[i] = 0.0f;
}

// ---------------------------------------------------------------- LN helper (block of 128 threads)
__device__ __forceinline__ float blk_norm(float v, int e, float* sred)
{
  float s = v;
  #pragma unroll
  for (int o = 1; o < 64; o <<= 1) s += __shfl_xor(s, o);
  if ((e & 63) == 0) sred[e >> 6] = s;
  __syncthreads();
  float mean = (sred[0] + sred[1]) * (1.0f / 128.0f);
  __syncthreads();
  float d = v - mean;
  float s2 = d * d;
  #pragma unroll
  for (int o = 1; o < 64; o <<= 1) s2 += __shfl_xor(s2, o);
  if ((e & 63) == 0) sred[e >> 6] = s2;
  __syncthreads();
  float var = (sred[0] + sred[1]) * (1.0f / 128.0f);
  __syncthreads();
  return d / sqrtf(var + 1e-5f);
}

// ---------------------------------------------------------------- node projection h = x @ gproj_w + b
__global__ __launch_bounds__(128) void node_proj_k(
    const float* __restrict__ cx, const float* __restrict__ sx,
    const float* __restrict__ w, const float* __restrict__ b, float* __restrict__ h)
{
  int r = blockIdx.x, e = threadIdx.x;
  const float* x = (r < 2048) ? (cx + (size_t)r * 64) : (sx + (size_t)(r - 2048) * 64);
  __shared__ float xs[64];
  if (e < 64) xs[e] = x[e];
  __syncthreads();
  float acc = b[e];
  for (int a = 0; a < 64; a++) acc += xs[a] * w[a * 128 + e];
  h[(size_t)r * 128 + e] = acc;
}

// ---------------------------------------------------------------- pairwise distance per graph
__global__ __launch_bounds__(256) void dist_k(
    const float* __restrict__ cpos, const float* __restrict__ spos, float* __restrict__ dist)
{
  int g = blockIdx.x, tid = threadIdx.x;
  __shared__ float P[96];
  const float* p = (g < 64) ? (cpos + (size_t)g * 96) : (spos + (size_t)(g - 64) * 96);
  if (tid < 96) P[tid] = p[tid];
  __syncthreads();
  #pragma unroll
  for (int jj = 0; jj < 4; jj++) {
    int idx = tid * 4 + jj;
    int i = idx >> 5, j = idx & 31;
    float dx = P[i * 3 + 0] - P[j * 3 + 0];
    float dy = P[i * 3 + 1] - P[j * 3 + 1];
    float dz = P[i * 3 + 2] - P[j * 3 + 2];
    float d2 = dx * dx + dy * dy + dz * dz;
    dist[(size_t)g * 1024 + idx] = (d2 > 0.0f) ? sqrtf(d2) : 0.0f;
  }
}

// ---------------------------------------------------------------- edge features + dst-node gather
__global__ __launch_bounds__(128) void edge_prep_k(
    const float* __restrict__ cea, const float* __restrict__ sea,
    const int* __restrict__ cei, const int* __restrict__ sei,
    const float* __restrict__ h, float* __restrict__ ef, float* __restrict__ hd)
{
  int m = blockIdx.x, e = threadIdx.x;
  const float* attr; int dst;
  if (m < 4096) { attr = cea + (size_t)m * 17; dst = cei[4096 + m]; }
  else { int m2 = m - 4096; attr = sea + (size_t)m2 * 17; dst = sei[1024 + m2] + 2048; }
  hd[(size_t)m * 128 + e] = h[(size_t)dst * 128 + e];
  if (e < 16) {
    ef[(size_t)m * 49 + e] = attr[e];
  } else if (e < 48) {
    int kk = e - 16;
    float d = fminf(fmaxf(attr[16], 0.0f), 10.0f);
    float ctr = (float)(kk * (5.0 / 31.0));
    float t = d - ctr;
    ef[(size_t)m * 49 + e] = expf(-38.44f * t * t);
  } else if (e == 48) {
    ef[(size_t)m * 49 + 48] = 1.0f;   // bias channel (elin_b has E*E elems, 49th K-row)
  }
}

// ---------------------------------------------------------------- EdgeNetwork GEMM + atomic scatter
// msg[m,e] = sum_{c<49} ef[m,c] * sum_f W_c[e*128+f] * hd[m,f]; W_48 = elin_b.
// grid.x: 32-edge tile; grid.y in {0,1}: K-split over kt=(c,fblock) 0..195.
__global__ __launch_bounds__(256) void edge_gemm_k(
    const float* __restrict__ ef, const float* __restrict__ hd,
    const float* __restrict__ elw, const float* __restrict__ elb,
    const int* __restrict__ cei, const int* __restrict__ sei, float* __restrict__ aggr)
{
  __shared__ float efs[32][49];
  __shared__ float hds[32][128];
  __shared__ float As[32][36];
  __shared__ float Bs[32][136];
  const int tid = threadIdx.x;
  const int m0 = blockIdx.x * 32;
  const int kt0 = blockIdx.y * 98;
  for (int i = tid; i < 32 * 49; i += 256) {
    int t = i / 49, c = i - t * 49;
    efs[t][c] = ef[(size_t)(m0 + t) * 49 + c];
  }
  for (int i = tid; i < 4096; i += 256) {
    int t = i >> 7, f = i & 127;
    hds[t][f] = hd[(size_t)(m0 + t) * 128 + f];
  }
  const int tn = tid & 31, tm = tid >> 5;
  const int e0 = 4 * tn, t0 = 4 * tm;
  const int gk = tid >> 3;          // As gen: k within tile
  const int gt = (tid & 7) * 4;     // As gen: edge offset
  const int se = tid >> 1;          // Bs stage: e (output col)
  const int sk = (tid & 1) * 16;    // Bs stage: k offset
  float acc[4][4] = {};
  __syncthreads();
  for (int kt = kt0; kt < kt0 + 98; kt++) {
    int c = kt >> 2, f0 = (kt & 3) * 32;
    As[gk][gt + 0] = efs[gt + 0][c] * hds[gt + 0][f0 + gk];
    As[gk][gt + 1] = efs[gt + 1][c] * hds[gt + 1][f0 + gk];
    As[gk][gt + 2] = efs[gt + 2][c] * hds[gt + 2][f0 + gk];
    As[gk][gt + 3] = efs[gt + 3][c] * hds[gt + 3][f0 + gk];
    const float* bp = ((c < 48) ? (elw + (size_t)c * 16384) : elb) + (size_t)se * 128 + f0 + sk;
    float4 w0 = *(const float4*)(bp + 0);
    float4 w1 = *(const float4*)(bp + 4);
    float4 w2 = *(const float4*)(bp + 8);
    float4 w3 = *(const float4*)(bp + 12);
    Bs[sk + 0][se] = w0.x;  Bs[sk + 1][se] = w0.y;  Bs[sk + 2][se] = w0.z;  Bs[sk + 3][se] = w0.w;
    Bs[sk + 4][se] = w1.x;  Bs[sk + 5][se] = w1.y;  Bs[sk + 6][se] = w1.z;  Bs[sk + 7][se] = w1.w;
    Bs[sk + 8][se] = w2.x;  Bs[sk + 9][se] = w2.y;  Bs[sk + 10][se] = w2.z; Bs[sk + 11][se] = w2.w;
    Bs[sk + 12][se] = w3.x; Bs[sk + 13][se] = w3.y; Bs[sk + 14][se] = w3.z; Bs[sk + 15][se] = w3.w;
    __syncthreads();
    #pragma unroll
    for (int kk = 0; kk < 32; kk++) {
      float a0 = As[kk][t0 + 0], a1 = As[kk][t0 + 1], a2 = As[kk][t0 + 2], a3 = As[kk][t0 + 3];
      float b0 = Bs[kk][e0 + 0], b1 = Bs[kk][e0 + 1], b2 = Bs[kk][e0 + 2], b3 = Bs[kk][e0 + 3];
      acc[0][0] += a0 * b0; acc[0][1] += a0 * b1; acc[0][2] += a0 * b2; acc[0][3] += a0 * b3;
      acc[1][0] += a1 * b0; acc[1][1] += a1 * b1; acc[1][2] += a1 * b2; acc[1][3] += a1 * b3;
      acc[2][0] += a2 * b0; acc[2][1] += a2 * b1; acc[2][2] += a2 * b2; acc[2][3] += a2 * b3;
      acc[3][0] += a3 * b0; acc[3][1] += a3 * b1; acc[3][2] += a3 * b2; acc[3][3] += a3 * b3;
    }
    __syncthreads();
  }
  #pragma unroll
  for (int i = 0; i < 4; i++) {
    int m = m0 + t0 + i;
    int src = (m < 4096) ? cei[m] : (sei[m - 4096] + 2048);
    float* dst = aggr + (size_t)src * 128 + e0;
    atomicAdd(dst + 0, acc[i][0]);
    atomicAdd(dst + 1, acc[i][1]);
    atomicAdd(dst + 2, acc[i][2]);
    atomicAdd(dst + 3, acc[i][3]);
  }
}

// ---------------------------------------------------------------- generic GEMM: C = act(A[M,K] @ B[K,N] + bias)
// BM=32, BN=128 (grid.x tiles N), BK=32, 4x4 micro. All fp32.
__global__ __launch_bounds__(256) void gemm_k(
    const float* __restrict__ A, const float* __restrict__ B,
    const float* __restrict__ bias, float* __restrict__ C,
    int M, int K, int N, int relu)
{
  __shared__ float As[32][36];
  __shared__ float Bs[32][136];
  const int tid = threadIdx.x;
  const int row0 = blockIdx.y * 32;
  const int n0 = blockIdx.x * 128;
  const int tn = tid & 31, tm = tid >> 5;
  const int e0 = 4 * tn, t0 = 4 * tm;
  const int ar = tid >> 3, ak = (tid & 7) * 4;
  const int bk = tid >> 3, be = (tid & 7) * 16;
  float acc[4][4] = {};
  for (int k0 = 0; k0 < K; k0 += 32) {
    const float* ap = A + (size_t)(row0 + ar) * K + k0 + ak;
    As[ak + 0][ar] = ap[0];
    As[ak + 1][ar] = ap[1];
    As[ak + 2][ar] = ap[2];
    As[ak + 3][ar] = ap[3];
    const float* bp = B + (size_t)(k0 + bk) * N + n0 + be;
    float4 b0v = *(const float4*)(bp + 0);
    float4 b1v = *(const float4*)(bp + 4);
    float4 b2v = *(const float4*)(bp + 8);
    float4 b3v = *(const float4*)(bp + 12);
    Bs[bk][be + 0] = b0v.x;  Bs[bk][be + 1] = b0v.y;  Bs[bk][be + 2] = b0v.z;  Bs[bk][be + 3] = b0v.w;
    Bs[bk][be + 4] = b1v.x;  Bs[bk][be + 5] = b1v.y;  Bs[bk][be + 6] = b1v.z;  Bs[bk][be + 7] = b1v.w;
    Bs[bk][be + 8] = b2v.x;  Bs[bk][be + 9] = b2v.y;  Bs[bk][be + 10] = b2v.z; Bs[bk][be + 11] = b2v.w;
    Bs[bk][be + 12] = b3v.x; Bs[bk][be + 13] = b3v.y; Bs[bk][be + 14] = b3v.z; Bs[bk][be + 15] = b3v.w;
    __syncthreads();
    #pragma unroll
    for (int kk = 0; kk < 32; kk++) {
      float a0 = As[kk][t0 + 0], a1 = As[kk][t0 + 1], a2 = As[kk][t0 + 2], a3 = As[kk][t0 + 3];
      float b0 = Bs[kk][e0 + 0], b1 = Bs[kk][e0 + 1], b2 = Bs[kk][e0 + 2], b3 = Bs[kk][e0 + 3];
      acc[0][0] += a0 * b0; acc[0][1] += a0 * b1; acc[0][2] += a0 * b2; acc[0][3] += a0 * b3;
      acc[1][0] += a1 * b0; acc[1][1] += a1 * b1; acc[1][2] += a1 * b2; acc[1][3] += a1 * b3;
      acc[2][0] += a2 * b0; acc[2][1] += a2 * b1; acc[2][2] += a2 * b2; acc[2][3] += a2 * b3;
      acc[3][0] += a3 * b0; acc[3][1] += a3 * b1; acc[3][2] += a3 * b2; acc[3][3] += a3 * b3;
    }
    __syncthreads();
  }
  #pragma unroll
  for (int i = 0; i < 4; i++) {
    float* cp = C + (size_t)(row0 + t0 + i) * N + n0 + e0;
    #pragma unroll
    for (int j = 0; j < 4; j++) {
      float c = acc[i][j] + bias[n0 + e0 + j];
      if (relu) c = fmaxf(c, 0.0f);
      cp[j] = c;
    }
  }
}

// ---------------------------------------------------------------- LayerNorm rows of 128: out = LN(x+res)*g+b
__global__ __launch_bounds__(128) void ln_k(
    const float* __restrict__ x, const float* __restrict__ res,
    const float* __restrict__ g, const float* __restrict__ b, float* __restrict__ out)
{
  __shared__ float sred[2];
  int r = blockIdx.x, e = threadIdx.x;
  size_t idx = (size_t)r * 128 + e;
  float v = x[idx] + res[idx];
  float nv = blk_norm(v, e, sred);
  out[idx] = nv * g[e] + b[e];
}

// ---------------------------------------------------------------- graph attention (N=32, GD=16) per (g,h)
__global__ __launch_bounds__(256) void gattn_k(
    const float* __restrict__ q, const float* __restrict__ k, const float* __restrict__ v,
    const float* __restrict__ dist, float* __restrict__ o)
{
  __shared__ float qs[32][17], ksh[32][17], vsh[32][17], ss[32][33], rs[32];
  const int g = blockIdx.x, h = blockIdx.y, tid = threadIdx.x;
  {
    int idx = tid * 2;
    int i = idx >> 4, d = idx & 15;
    size_t base = ((size_t)(g * 32 + i)) * 128 + h * 16 + d;
    qs[i][d] = q[base];  qs[i][d + 1] = q[base + 1];
    ksh[i][d] = k[base]; ksh[i][d + 1] = k[base + 1];
    vsh[i][d] = v[base]; vsh[i][d + 1] = v[base + 1];
  }
  __syncthreads();
  {
    int i = tid >> 3, j0 = (tid & 7) * 4;
    for (int j = j0; j < j0 + 4; j++) {
      float a = 0;
      #pragma unroll
      for (int d = 0; d < 16; d++) a += qs[i][d] * ksh[j][d];
      a = a * 0.25f + dist[(size_t)g * 1024 + i * 32 + j];
      ss[i][j] = fminf(fmaxf(a, -10.0f), 10.0f);
    }
  }
  __syncthreads();
  if (tid < 32) {
    float m = -1e30f;
    for (int j = 0; j < 32; j++) m = fmaxf(m, ss[tid][j]);
    float sm = 0;
    for (int j = 0; j < 32; j++) { float ex = expf(ss[tid][j] - m); ss[tid][j] = ex; sm += ex; }
    rs[tid] = 1.0f / sm;
  }
  __syncthreads();
  {
    int idx = tid * 2;
    int i = idx >> 4, d = idx & 15;
    float a0 = 0, a1 = 0;
    for (int j = 0; j < 32; j++) { float wj = ss[i][j]; a0 += wj * vsh[j][d]; a1 += wj * vsh[j][d + 1]; }
    float r = rs[i];
    size_t base = ((size_t)(g * 32 + i)) * 128 + h * 16 + d;
    o[base] = a0 * r; o[base + 1] = a1 * r;
  }
}

// ---------------------------------------------------------------- sequence attention (L=128, SD=32) per (b,h,qtile)
__global__ __launch_bounds__(256) void sattn_k(const float* __restrict__ qkv, float* __restrict__ o)
{
  __shared__ float ks[128][33];
  __shared__ float vs[128][33];
  __shared__ float qs[32][33];
  __shared__ float ss[32][129];
  __shared__ float red[32][8];
  __shared__ float red2[32][8];
  const int b = blockIdx.x, h = blockIdx.y, qt = blockIdx.z, tid = threadIdx.x;
  {
    int l = tid >> 1, d0 = (tid & 1) * 16;
    const float* kp = qkv + ((size_t)(b * 128 + l)) * 384 + 128 + h * 32 + d0;
    #pragma unroll
    for (int j = 0; j < 16; j++) { ks[l][d0 + j] = kp[j]; vs[l][d0 + j] = kp[128 + j]; }
  }
  {
    int i = tid >> 3, d0 = (tid & 7) * 4;
    const float* qp = qkv + ((size_t)(b * 128 + qt * 32 + i)) * 384 + h * 32 + d0;
    #pragma unroll
    for (int j = 0; j < 4; j++) qs[i][d0 + j] = qp[j];
  }
  __syncthreads();
  const int i = tid >> 3, sub = tid & 7;
  {
    int j0 = sub * 16;
    for (int j = j0; j < j0 + 16; j++) {
      float a = 0;
      #pragma unroll
      for (int d = 0; d < 32; d++) a += qs[i][d] * ks[j][d];
      ss[i][j] = a * 0.17677669529663687f;   // 1/sqrt(32)
    }
  }
  __syncthreads();
  float m = -1e30f;
  for (int j = sub; j < 128; j += 8) m = fmaxf(m, ss[i][j]);
  red[i][sub] = m;
  __syncthreads();
  float mm = red[i][0];
  #pragma unroll
  for (int t = 1; t < 8; t++) mm = fmaxf(mm, red[i][t]);
  float ps = 0;
  for (int j = sub; j < 128; j += 8) { float ex = expf(ss[i][j] - mm); ss[i][j] = ex; ps += ex; }
  red2[i][sub] = ps;
  __syncthreads();
  float sm = 0;
  #pragma unroll
  for (int t = 0; t < 8; t++) sm += red2[i][t];
  float rinv = 1.0f / sm;
  {
    int d0 = sub * 4;
    float a0 = 0, a1 = 0, a2 = 0, a3 = 0;
    for (int j = 0; j < 128; j++) {
      float wj = ss[i][j];
      a0 += wj * vs[j][d0 + 0]; a1 += wj * vs[j][d0 + 1];
      a2 += wj * vs[j][d0 + 2]; a3 += wj * vs[j][d0 + 3];
    }
    float* op = o + ((size_t)(b * 128 + qt * 32 + i)) * 128 + h * 32 + d0;
    op[0] = a0 * rinv; op[1] = a1 * rinv; op[2] = a2 * rinv; op[3] = a3 * rinv;
  }
}

// ---------------------------------------------------------------- embedding
__global__ __launch_bounds__(128) void embed_k(
    const int* __restrict__ tokens, const float* __restrict__ tok_emb,
    const float* __restrict__ pos_emb, float* __restrict__ xs)
{
  int r = blockIdx.x, e = threadIdx.x;
  int tk = tokens[r];
  xs[(size_t)r * 128 + e] = tok_emb[(size_t)tk * 128 + e] + pos_emb[(size_t)(r & 127) * 128 + e];
}

// ---------------------------------------------------------------- graph pool: total[mol] = mean4(conf) + scaf
__global__ __launch_bounds__(128) void pool_k(const float* __restrict__ hb, float* __restrict__ total)
{
  int mol = blockIdx.x, e = threadIdx.x;
  float cs = 0;
  for (int c = 0; c < 4; c++) {
    int g = mol * 4 + c;
    float s = 0;
    for (int i = 0; i < 32; i++) s += hb[((size_t)(g * 32 + i)) * 128 + e];
    cs += s * (1.0f / 32.0f);
  }
  cs *= 0.25f;
  float s2 = 0;
  int g = 64 + mol;
  for (int i = 0; i < 32; i++) s2 += hb[((size_t)(g * 32 + i)) * 128 + e];
  total[mol * 128 + e] = cs + s2 * (1.0f / 32.0f);
}

// ---------------------------------------------------------------- sequence mean over L
__global__ __launch_bounds__(128) void smean_k(const float* __restrict__ xs, float* __restrict__ seqm)
{
  int b = blockIdx.x, e = threadIdx.x;
  float s = 0;
  for (int l = 0; l < 128; l++) s += xs[((size_t)(b * 128 + l)) * 128 + e];
  seqm[b * 128 + e] = s * (1.0f / 128.0f);
}

// ---------------------------------------------------------------- fusion gate + cross-modal + regressor head
__global__ __launch_bounds__(128) void head_k(
    const float* __restrict__ total, const float* __restrict__ seqm, const float* __restrict__ gfeat,
    const float* fg1w, const float* fg1b, const float* fg2w, const float* fg2b,
    const float* g2s_vw, const float* g2s_vb, const float* g2s_ow, const float* g2s_ob,
    const float* n1g, const float* n1b,
    const float* s2g_vw, const float* s2g_vb, const float* s2g_ow, const float* s2g_ob,
    const float* n2g, const float* n2b,
    const float* r1w, const float* r1b, const float* r2w, const float* r2b,
    const float* __restrict__ hb_probe, const float* __restrict__ xs_probe,
    float* __restrict__ out)
{
  __shared__ float T[128], S[128], G[128], Sm[128], t1[128], t2[128], gh[64], sred[2];
  int mol = blockIdx.x, e = threadIdx.x;
  T[e] = total[mol * 128 + e];
  S[e] = seqm[mol * 128 + e];
  __syncthreads();
  if (e < 64) {
    float a = fg1b[e];
    for (int f = 0; f < 128; f++) a += T[f] * fg1w[f * 64 + e];
    for (int f = 0; f < 128; f++) a += S[f] * fg1w[(128 + f) * 64 + e];
    gh[e] = fmaxf(a, 0.0f);
  }
  __syncthreads();
  {
    float a = fg2b[e];
    for (int j = 0; j < 64; j++) a += gh[j] * fg2w[j * 128 + e];
    float gate = 1.0f / (1.0f + expf(-a));
    float fu = gate * T[e] + (1.0f - gate) * S[e];
    G[e] = fu; Sm[e] = fu;
  }
  __syncthreads();
  for (int l = 0; l < 2; l++) {
    const float* vw = g2s_vw + (size_t)l * 16384; const float* vb = g2s_vb + l * 128;
    const float* ow = g2s_ow + (size_t)l * 16384; const float* ob = g2s_ob + l * 128;
    float a = vb[e];
    for (int f = 0; f < 128; f++) a += Sm[f] * vw[f * 128 + e];
    t1[e] = a;
    __syncthreads();
    a = ob[e];
    for (int f = 0; f < 128; f++) a += t1[f] * ow[f * 128 + e];
    float nv = blk_norm(G[e] + a, e, sred);
    G[e] = nv * n1g[l * 128 + e] + n1b[l * 128 + e];
    __syncthreads();
    const float* vw2 = s2g_vw + (size_t)l * 16384; const float* vb2 = s2g_vb + l * 128;
    const float* ow2 = s2g_ow + (size_t)l * 16384; const float* ob2 = s2g_ob + l * 128;
    a = vb2[e];
    for (int f = 0; f < 128; f++) a += G[f] * vw2[f * 128 + e];
    t1[e] = a;
    __syncthreads();
    a = ob2[e];
    for (int f = 0; f < 128; f++) a += t1[f] * ow2[f * 128 + e];
    nv = blk_norm(Sm[e] + a, e, sred);
    Sm[e] = nv * n2g[l * 128 + e] + n2b[l * 128 + e];
    __syncthreads();
  }
  t2[e] = 0.5f * (G[e] + Sm[e]);
  __syncthreads();
  float a = r1b[e];
  for (int f = 0; f < 128; f++) a += t2[f] * r1w[f * 128 + e];
  for (int f = 0; f < 3; f++) a += gfeat[mol * 3 + f] * r1w[(128 + f) * 128 + e];
  a = fmaxf(a, 0.0f);
  float p = a * r2w[e];
  #pragma unroll
  for (int o = 1; o < 64; o <<= 1) p += __shfl_xor(p, o);
  if ((e & 63) == 0) sred[e >> 6] = p;
  __syncthreads();
  if (e == 0) {
    float result = sred[0] + sred[1] + r2b[0];
    if (!isfinite(result)) {
      // diagnostic sentinel: 512 + flag, decodable from reported absmax
      float flag = 0.0f;
      if (!isfinite(hb_probe[(size_t)mol * 128])) flag += 1.0f;   // graph path poisoned
      if (!isfinite(xs_probe[(size_t)mol * 128])) flag += 2.0f;   // seq path poisoned
      if (!isfinite(T[0])) flag += 4.0f;                          // pooled graph emb
      if (!isfinite(S[0])) flag += 8.0f;                          // pooled seq emb
      result = 512.0f + flag;
    }
    out[mol] = result;
  }
}

// ================================================================ host
extern "C" void kernel_launch(void* const* d_in, const int* in_sizes, int n_in,
                              void* d_out, int out_size, void* d_ws, size_t ws_size,
                              hipStream_t stream)
{
  (void)n_in; (void)out_size; (void)ws_size;
  // Inputs in setup_inputs() dict order; fallback to reference-signature order if
  // in_sizes[1] != 8192 (conf_edge_index flat count in dict order).
  const bool dict = (in_sizes[1] == 8192);
  auto IN = [&](int di, int si) { return d_in[dict ? di : si]; };

  const float* conf_x   = (const float*)IN(0, 0);
  const int*   conf_ei  = (const int*)  IN(1, 63);
  const float* conf_ea  = (const float*)IN(2, 1);
  const float* conf_pos = (const float*)IN(3, 2);
  const float* scaf_x   = (const float*)IN(4, 3);
  const int*   scaf_ei  = (const int*)  IN(5, 64);
  const float* scaf_ea  = (const float*)IN(6, 4);
  const float* scaf_pos = (const float*)IN(7, 5);
  const int*   tokens   = (const int*)  IN(8, 65);
  const float* gfeat    = (const float*)IN(9, 6);
  const float* gproj_w  = (const float*)IN(11, 7);
  const float* gproj_b  = (const float*)IN(12, 8);
  const float* elin_w   = (const float*)IN(13, 9);
  const float* elin_b   = (const float*)IN(14, 10);
  const float* eln_g    = (const float*)IN(15, 11);
  const float* eln_b    = (const float*)IN(16, 12);
  const float* gt_qw    = (const float*)IN(17, 13);
  const float* gt_qb    = (const float*)IN(18, 14);
  const float* gt_kw    = (const float*)IN(19, 15);
  const float* gt_kb    = (const float*)IN(20, 16);
  const float* gt_vw    = (const float*)IN(21, 17);
  const float* gt_vb    = (const float*)IN(22, 18);
  const float* gt_ow    = (const float*)IN(23, 19);
  const float* gt_ob    = (const float*)IN(24, 20);
  const float* gt_ln1g  = (const float*)IN(25, 21);
  const float* gt_ln1b  = (const float*)IN(26, 22);
  const float* gt_f1w   = (const float*)IN(27, 23);
  const float* gt_f1b   = (const float*)IN(28, 24);
  const float* gt_f2w   = (const float*)IN(29, 25);
  const float* gt_f2b   = (const float*)IN(30, 26);
  const float* gt_ln2g  = (const float*)IN(31, 27);
  const float* gt_ln2b  = (const float*)IN(32, 28);
  const float* tok_emb  = (const float*)IN(33, 29);
  const float* pos_emb  = (const float*)IN(34, 30);
  const float* se_inw   = (const float*)IN(35, 31);
  const float* se_inb   = (const float*)IN(36, 32);
  const float* se_ow    = (const float*)IN(37, 33);
  const float* se_ob    = (const float*)IN(38, 34);
  const float* se_ln1g  = (const float*)IN(39, 35);
  const float* se_ln1b  = (const float*)IN(40, 36);
  const float* se_f1w   = (const float*)IN(41, 37);
  const float* se_f1b   = (const float*)IN(42, 38);
  const float* se_f2w   = (const float*)IN(43, 39);
  const float* se_f2b   = (const float*)IN(44, 40);
  const float* se_ln2g  = (const float*)IN(45, 41);
  const float* se_ln2b  = (const float*)IN(46, 42);
  const float* fg1_w    = (const float*)IN(47, 43);
  const float* fg1_b    = (const float*)IN(48, 44);
  const float* fg2_w    = (const float*)IN(49, 45);
  const float* fg2_b    = (const float*)IN(50, 46);
  const float* cm_g2s_vw = (const float*)IN(51, 47);
  const float* cm_g2s_vb = (const float*)IN(52, 48);
  const float* cm_g2s_ow = (const float*)IN(53, 49);
  const float* cm_g2s_ob = (const float*)IN(54, 50);
  const float* cm_s2g_vw = (const float*)IN(55, 53);
  const float* cm_s2g_vb = (const float*)IN(56, 54);
  const float* cm_s2g_ow = (const float*)IN(57, 55);
  const float* cm_s2g_ob = (const float*)IN(58, 56);
  const float* cm_n1g   = (const float*)IN(59, 51);
  const float* cm_n1b   = (const float*)IN(60, 52);
  const float* cm_n2g   = (const float*)IN(61, 57);
  const float* cm_n2b   = (const float*)IN(62, 58);
  const float* r1_w     = (const float*)IN(63, 59);
  const float* r1_b     = (const float*)IN(64, 60);
  const float* r2_w     = (const float*)IN(65, 61);
  const float* r2_b     = (const float*)IN(66, 62);
  float* out = (float*)d_out;   // fp32 output per reference

  // ---- workspace layout (fp32) ----
  float* w = (float*)d_ws;
  size_t off = 0;
  auto alloc = [&](size_t n) { float* p = w + off; off += n; return p; };
  float* h     = alloc(2560 * 128);
  float* aggr  = alloc(2560 * 128);
  float* hb    = alloc(2560 * 128);
  float* distb = alloc(80 * 1024);
  float* gtmp  = alloc(2949120);        // shared region: edge bufs, graph temps, seq temps
  float* totalb = alloc(16 * 128);
  float* seqmb  = alloc(16 * 128);
  float* xsfin  = alloc(2048 * 128);    // final seq state kept for probe + smean
  // edge phase carve
  float* efb = gtmp;                    // 5120*49 = 250880
  float* hdb = gtmp + 250880;           // 5120*128 = 655360
  // graph-layer carve
  float* qb    = gtmp;
  float* kb    = gtmp + 327680;
  float* vb    = gtmp + 655360;
  float* atto  = gtmp + 983040;
  float* oproj = gtmp + 1310720;
  float* x1b   = gtmp + 1638400;
  float* ffh   = gtmp + 1966080;        // 2560*256
  float* ffo   = gtmp + 2621440;
  // seq carve
  float* xs2    = gtmp;                 // 2048*128
  float* qkv3   = gtmp + 262144;        // 2048*384
  float* satto  = gtmp + 1048576;
  float* soproj = gtmp + 1310720;
  float* sx1    = gtmp + 1572864;
  float* sffh   = gtmp + 1835008;       // 2048*256
  float* sffo   = gtmp + 2359296;

  // ============ graph encoder (conf rows 0..2047, scaf rows 2048..2559) ============
  node_proj_k<<<2560, 128, 0, stream>>>(conf_x, scaf_x, gproj_w, gproj_b, h);
  dist_k<<<80, 256, 0, stream>>>(conf_pos, scaf_pos, distb);
  edge_prep_k<<<5120, 128, 0, stream>>>(conf_ea, scaf_ea, conf_ei, scaf_ei, h, efb, hdb);
  zero_k<<<1280, 256, 0, stream>>>(aggr, 2560 * 128);
  edge_gemm_k<<<dim3(160, 2), 256, 0, stream>>>(efb, hdb, elin_w, elin_b, conf_ei, scaf_ei, aggr);
  ln_k<<<2560, 128, 0, stream>>>(aggr, h, eln_g, eln_b, hb);

  for (int l = 0; l < 3; l++) {
    gemm_k<<<dim3(1, 80), 256, 0, stream>>>(hb, gt_qw + (size_t)l * 16384, gt_qb + l * 128, qb, 2560, 128, 128, 0);
    gemm_k<<<dim3(1, 80), 256, 0, stream>>>(hb, gt_kw + (size_t)l * 16384, gt_kb + l * 128, kb, 2560, 128, 128, 0);
    gemm_k<<<dim3(1, 80), 256, 0, stream>>>(hb, gt_vw + (size_t)l * 16384, gt_vb + l * 128, vb, 2560, 128, 128, 0);
    gattn_k<<<dim3(80, 8), 256, 0, stream>>>(qb, kb, vb, distb, atto);
    gemm_k<<<dim3(1, 80), 256, 0, stream>>>(atto, gt_ow + (size_t)l * 16384, gt_ob + l * 128, oproj, 2560, 128, 128, 0);
    ln_k<<<2560, 128, 0, stream>>>(oproj, hb, gt_ln1g + l * 128, gt_ln1b + l * 128, x1b);
    gemm_k<<<dim3(2, 80), 256, 0, stream>>>(x1b, gt_f1w + (size_t)l * 32768, gt_f1b + l * 256, ffh, 2560, 128, 256, 1);
    gemm_k<<<dim3(1, 80), 256, 0, stream>>>(ffh, gt_f2w + (size_t)l * 32768, gt_f2b + l * 128, ffo, 2560, 256, 128, 0);
    ln_k<<<2560, 128, 0, stream>>>(ffo, x1b, gt_ln2g + l * 128, gt_ln2b + l * 128, hb);
  }
  pool_k<<<16, 128, 0, stream>>>(hb, totalb);

  // ============ sequence encoder ============
  embed_k<<<2048, 128, 0, stream>>>(tokens, tok_emb, pos_emb, xs2);
  for (int l = 0; l < 4; l++) {
    gemm_k<<<dim3(3, 64), 256, 0, stream>>>(xs2, se_inw + (size_t)l * 49152, se_inb + l * 384, qkv3, 2048, 128, 384, 0);
    sattn_k<<<dim3(16, 4, 4), 256, 0, stream>>>(qkv3, satto);
    gemm_k<<<dim3(1, 64), 256, 0, stream>>>(satto, se_ow + (size_t)l * 16384, se_ob + l * 128, soproj, 2048, 128, 128, 0);
    ln_k<<<2048, 128, 0, stream>>>(soproj, xs2, se_ln1g + l * 128, se_ln1b + l * 128, sx1);
    gemm_k<<<dim3(2, 64), 256, 0, stream>>>(sx1, se_f1w + (size_t)l * 32768, se_f1b + l * 256, sffh, 2048, 128, 256, 1);
    gemm_k<<<dim3(1, 64), 256, 0, stream>>>(sffh, se_f2w + (size_t)l * 32768, se_f2b + l * 128, sffo, 2048, 256, 128, 0);
    ln_k<<<2048, 128, 0, stream>>>(sffo, sx1, se_ln2g + l * 128, se_ln2b + l * 128,
                                   (l == 3) ? xsfin : xs2);
  }
  smean_k<<<16, 128, 0, stream>>>(xsfin, seqmb);

  // ============ fusion + cross-modal + regressor ============
  head_k<<<16, 128, 0, stream>>>(totalb, seqmb, gfeat,
                                 fg1_w, fg1_b, fg2_w, fg2_b,
                                 cm_g2s_vw, cm_g2s_vb, cm_g2s_ow, cm_g2s_ob, cm_n1g, cm_n1b,
                                 cm_s2g_vw, cm_s2g_vb, cm_s2g_ow, cm_s2g_ob, cm_n2g, cm_n2b,
                                 r1_w, r1_b, r2_w, r2_b,
                                 hb, xsfin, out);
}

// Round 5
// 851.882 us; speedup vs baseline: 1.1939x; 1.1939x over previous
//
#include <hip/hip_runtime.h>
#include <hip/hip_bf16.h>

// ---------------------------------------------------------------- constants
// E=128 GH=8 GD=16 GL=3 | SH=4 SD=32 SL=4 | N=32 GC=64 GS=16 DEG=64 BMOL=16
// M_conf=4096 M_scaf=1024 M_tot=5120. All float tensors fp32.

// ---------------------------------------------------------------- zero fill
__global__ __launch_bounds__(256) void zero_k(float* __restrict__ p, int n)
{
  int i = blockIdx.x * 256 + threadIdx.x;
  if (i < n) p[i] = 0.0f;
}

// ---------------------------------------------------------------- LN helper (block of 128 threads)
__device__ __forceinline__ float blk_norm(float v, int e, float* sred)
{
  float s = v;
  #pragma unroll
  for (int o = 1; o < 64; o <<= 1) s += __shfl_xor(s, o);
  if ((e & 63) == 0) sred[e >> 6] = s;
  __syncthreads();
  float mean = (sred[0] + sred[1]) * (1.0f / 128.0f);
  __syncthreads();
  float d = v - mean;
  float s2 = d * d;
  #pragma unroll
  for (int o = 1; o < 64; o <<= 1) s2 += __shfl_xor(s2, o);
  if ((e & 63) == 0) sred[e >> 6] = s2;
  __syncthreads();
  float var = (sred[0] + sred[1]) * (1.0f / 128.0f);
  __syncthreads();
  return d / sqrtf(var + 1e-5f);
}

// ---------------------------------------------------------------- node projection h = x @ gproj_w + b
__global__ __launch_bounds__(128) void node_proj_k(
    const float* __restrict__ cx, const float* __restrict__ sx,
    const float* __restrict__ w, const float* __restrict__ b, float* __restrict__ h)
{
  int r = blockIdx.x, e = threadIdx.x;
  const float* x = (r < 2048) ? (cx + (size_t)r * 64) : (sx + (size_t)(r - 2048) * 64);
  __shared__ float xs[64];
  if (e < 64) xs[e] = x[e];
  __syncthreads();
  float acc = b[e];
  for (int a = 0; a < 64; a++) acc += xs[a] * w[a * 128 + e];
  h[(size_t)r * 128 + e] = acc;
}

// ---------------------------------------------------------------- pairwise distance per graph
__global__ __launch_bounds__(256) void dist_k(
    const float* __restrict__ cpos, const float* __restrict__ spos, float* __restrict__ dist)
{
  int g = blockIdx.x, tid = threadIdx.x;
  __shared__ float P[96];
  const float* p = (g < 64) ? (cpos + (size_t)g * 96) : (spos + (size_t)(g - 64) * 96);
  if (tid < 96) P[tid] = p[tid];
  __syncthreads();
  #pragma unroll
  for (int jj = 0; jj < 4; jj++) {
    int idx = tid * 4 + jj;
    int i = idx >> 5, j = idx & 31;
    float dx = P[i * 3 + 0] - P[j * 3 + 0];
    float dy = P[i * 3 + 1] - P[j * 3 + 1];
    float dz = P[i * 3 + 2] - P[j * 3 + 2];
    float d2 = dx * dx + dy * dy + dz * dz;
    dist[(size_t)g * 1024 + idx] = (d2 > 0.0f) ? sqrtf(d2) : 0.0f;
  }
}

// ---------------------------------------------------------------- EdgeNetwork GEMM (fused prep) + atomic scatter
// msg[m,e] = sum_{c<49} ef[m,c] * dot(W_c[e,:], h[dst[m]]); W_48 = elin_b.
// ef: 16 bond + 32 RBF + 1 bias-channel, computed inline. grid (160, 8): 32-edge tile x K-chunk.
__global__ __launch_bounds__(256) void edge_gemm_k(
    const float* __restrict__ cea, const float* __restrict__ sea,
    const int* __restrict__ cei, const int* __restrict__ sei,
    const float* __restrict__ h,
    const float* __restrict__ elw, const float* __restrict__ elb,
    float* __restrict__ aggr)
{
  __shared__ float efs[32][50];
  __shared__ float hds[32][128];
  __shared__ float As[32][33];
  __shared__ float Bs[32][136];
  __shared__ int srcs[32], dsts[32];
  const int tid = threadIdx.x;
  const int m0 = blockIdx.x * 32;
  const int kt0 = blockIdx.y * 25;
  const int ktend = (kt0 + 25 < 196) ? (kt0 + 25) : 196;
  if (tid < 32) {
    int m = m0 + tid;
    int src, dst;
    if (m < 4096) { src = cei[m]; dst = cei[4096 + m]; }
    else { src = sei[m - 4096] + 2048; dst = sei[1024 + (m - 4096)] + 2048; }
    srcs[tid] = src; dsts[tid] = dst;
  }
  __syncthreads();
  for (int i = tid; i < 4096; i += 256) {
    int t = i >> 7, f = i & 127;
    hds[t][f] = h[(size_t)dsts[t] * 128 + f];
  }
  for (int i = tid; i < 32 * 49; i += 256) {
    int t = i / 49, c = i - t * 49;
    int m = m0 + t;
    const float* attr = (m < 4096) ? (cea + (size_t)m * 17) : (sea + (size_t)(m - 4096) * 17);
    float val;
    if (c < 16) val = attr[c];
    else if (c < 48) {
      float d = fminf(fmaxf(attr[16], 0.0f), 10.0f);
      float t2 = d - (float)((c - 16) * (5.0 / 31.0));
      val = expf(-38.44f * t2 * t2);           // gamma = (31/5)^2 exactly
    } else val = 1.0f;
    efs[t][c] = val;
  }
  const int tn = tid & 31, tm = tid >> 5;
  const int e0 = 4 * tn, t0 = 4 * tm;
  const int gk = tid & 31;          // As gen: k lane (conflict-free hds read)
  const int gt = (tid >> 5) * 4;    // As gen: edge offset
  const int se = tid >> 1;          // Bs stage: e (output col)
  const int sk = (tid & 1) * 16;    // Bs stage: k offset
  float acc[4][4] = {};
  __syncthreads();
  for (int kt = kt0; kt < ktend; kt++) {
    int c = kt >> 2, f0 = (kt & 3) * 32;
    #pragma unroll
    for (int i = 0; i < 4; i++)
      As[gk][gt + i] = efs[gt + i][c] * hds[gt + i][f0 + gk];
    const float* bp = ((c < 48) ? (elw + (size_t)c * 16384) : elb) + (size_t)se * 128 + f0 + sk;
    float4 w0 = *(const float4*)(bp + 0);
    float4 w1 = *(const float4*)(bp + 4);
    float4 w2 = *(const float4*)(bp + 8);
    float4 w3 = *(const float4*)(bp + 12);
    Bs[sk + 0][se] = w0.x;  Bs[sk + 1][se] = w0.y;  Bs[sk + 2][se] = w0.z;  Bs[sk + 3][se] = w0.w;
    Bs[sk + 4][se] = w1.x;  Bs[sk + 5][se] = w1.y;  Bs[sk + 6][se] = w1.z;  Bs[sk + 7][se] = w1.w;
    Bs[sk + 8][se] = w2.x;  Bs[sk + 9][se] = w2.y;  Bs[sk + 10][se] = w2.z; Bs[sk + 11][se] = w2.w;
    Bs[sk + 12][se] = w3.x; Bs[sk + 13][se] = w3.y; Bs[sk + 14][se] = w3.z; Bs[sk + 15][se] = w3.w;
    __syncthreads();
    #pragma unroll
    for (int kk = 0; kk < 32; kk++) {
      float a0 = As[kk][t0 + 0], a1 = As[kk][t0 + 1], a2 = As[kk][t0 + 2], a3 = As[kk][t0 + 3];
      float b0 = Bs[kk][e0 + 0], b1 = Bs[kk][e0 + 1], b2 = Bs[kk][e0 + 2], b3 = Bs[kk][e0 + 3];
      acc[0][0] += a0 * b0; acc[0][1] += a0 * b1; acc[0][2] += a0 * b2; acc[0][3] += a0 * b3;
      acc[1][0] += a1 * b0; acc[1][1] += a1 * b1; acc[1][2] += a1 * b2; acc[1][3] += a1 * b3;
      acc[2][0] += a2 * b0; acc[2][1] += a2 * b1; acc[2][2] += a2 * b2; acc[2][3] += a2 * b3;
      acc[3][0] += a3 * b0; acc[3][1] += a3 * b1; acc[3][2] += a3 * b2; acc[3][3] += a3 * b3;
    }
    __syncthreads();
  }
  #pragma unroll
  for (int i = 0; i < 4; i++) {
    float* dst = aggr + (size_t)srcs[t0 + i] * 128 + e0;
    atomicAdd(dst + 0, acc[i][0]);
    atomicAdd(dst + 1, acc[i][1]);
    atomicAdd(dst + 2, acc[i][2]);
    atomicAdd(dst + 3, acc[i][3]);
  }
}

// ---------------------------------------------------------------- generic GEMM: C = act(A[M,K] @ B[K,N] + bias)
__global__ __launch_bounds__(256) void gemm_k(
    const float* __restrict__ A, const float* __restrict__ B,
    const float* __restrict__ bias, float* __restrict__ C,
    int K, int N, int relu)
{
  __shared__ float As[32][36];
  __shared__ float Bs[32][136];
  const int tid = threadIdx.x;
  const int row0 = blockIdx.y * 32;
  const int n0 = blockIdx.x * 128;
  const int tn = tid & 31, tm = tid >> 5;
  const int e0 = 4 * tn, t0 = 4 * tm;
  const int ar = tid >> 3, ak = (tid & 7) * 4;
  const int bk = tid >> 3, be = (tid & 7) * 16;
  float acc[4][4] = {};
  for (int k0 = 0; k0 < K; k0 += 32) {
    const float* ap = A + (size_t)(row0 + ar) * K + k0 + ak;
    float4 av = *(const float4*)ap;
    As[ak + 0][ar] = av.x; As[ak + 1][ar] = av.y; As[ak + 2][ar] = av.z; As[ak + 3][ar] = av.w;
    const float* bp = B + (size_t)(k0 + bk) * N + n0 + be;
    float4 b0v = *(const float4*)(bp + 0);
    float4 b1v = *(const float4*)(bp + 4);
    float4 b2v = *(const float4*)(bp + 8);
    float4 b3v = *(const float4*)(bp + 12);
    Bs[bk][be + 0] = b0v.x;  Bs[bk][be + 1] = b0v.y;  Bs[bk][be + 2] = b0v.z;  Bs[bk][be + 3] = b0v.w;
    Bs[bk][be + 4] = b1v.x;  Bs[bk][be + 5] = b1v.y;  Bs[bk][be + 6] = b1v.z;  Bs[bk][be + 7] = b1v.w;
    Bs[bk][be + 8] = b2v.x;  Bs[bk][be + 9] = b2v.y;  Bs[bk][be + 10] = b2v.z; Bs[bk][be + 11] = b2v.w;
    Bs[bk][be + 12] = b3v.x; Bs[bk][be + 13] = b3v.y; Bs[bk][be + 14] = b3v.z; Bs[bk][be + 15] = b3v.w;
    __syncthreads();
    #pragma unroll
    for (int kk = 0; kk < 32; kk++) {
      float a0 = As[kk][t0 + 0], a1 = As[kk][t0 + 1], a2 = As[kk][t0 + 2], a3 = As[kk][t0 + 3];
      float b0 = Bs[kk][e0 + 0], b1 = Bs[kk][e0 + 1], b2 = Bs[kk][e0 + 2], b3 = Bs[kk][e0 + 3];
      acc[0][0] += a0 * b0; acc[0][1] += a0 * b1; acc[0][2] += a0 * b2; acc[0][3] += a0 * b3;
      acc[1][0] += a1 * b0; acc[1][1] += a1 * b1; acc[1][2] += a1 * b2; acc[1][3] += a1 * b3;
      acc[2][0] += a2 * b0; acc[2][1] += a2 * b1; acc[2][2] += a2 * b2; acc[2][3] += a2 * b3;
      acc[3][0] += a3 * b0; acc[3][1] += a3 * b1; acc[3][2] += a3 * b2; acc[3][3] += a3 * b3;
    }
    __syncthreads();
  }
  #pragma unroll
  for (int i = 0; i < 4; i++) {
    float* cp = C + (size_t)(row0 + t0 + i) * N + n0 + e0;
    #pragma unroll
    for (int j = 0; j < 4; j++) {
      float c = acc[i][j] + bias[n0 + e0 + j];
      if (relu) c = fmaxf(c, 0.0f);
      cp[j] = c;
    }
  }
}

// ---------------------------------------------------------------- fused QKV GEMM (graph): z = blockIdx.x selects weights
__global__ __launch_bounds__(256) void gemm3_k(
    const float* __restrict__ A,
    const float* __restrict__ Bq, const float* __restrict__ Bk, const float* __restrict__ Bv,
    const float* __restrict__ bq, const float* __restrict__ bk_, const float* __restrict__ bv,
    float* __restrict__ Cbase, int cstride)
{
  const int z = blockIdx.x;
  const float* B = (z == 0) ? Bq : (z == 1) ? Bk : Bv;
  const float* bias = (z == 0) ? bq : (z == 1) ? bk_ : bv;
  float* C = Cbase + (size_t)z * cstride;
  __shared__ float As[32][36];
  __shared__ float Bs[32][136];
  const int tid = threadIdx.x;
  const int row0 = blockIdx.y * 32;
  const int tn = tid & 31, tm = tid >> 5;
  const int e0 = 4 * tn, t0 = 4 * tm;
  const int ar = tid >> 3, ak = (tid & 7) * 4;
  const int bk = tid >> 3, be = (tid & 7) * 16;
  float acc[4][4] = {};
  for (int k0 = 0; k0 < 128; k0 += 32) {
    float4 av = *(const float4*)(A + (size_t)(row0 + ar) * 128 + k0 + ak);
    As[ak + 0][ar] = av.x; As[ak + 1][ar] = av.y; As[ak + 2][ar] = av.z; As[ak + 3][ar] = av.w;
    const float* bp = B + (size_t)(k0 + bk) * 128 + be;
    float4 b0v = *(const float4*)(bp + 0);
    float4 b1v = *(const float4*)(bp + 4);
    float4 b2v = *(const float4*)(bp + 8);
    float4 b3v = *(const float4*)(bp + 12);
    Bs[bk][be + 0] = b0v.x;  Bs[bk][be + 1] = b0v.y;  Bs[bk][be + 2] = b0v.z;  Bs[bk][be + 3] = b0v.w;
    Bs[bk][be + 4] = b1v.x;  Bs[bk][be + 5] = b1v.y;  Bs[bk][be + 6] = b1v.z;  Bs[bk][be + 7] = b1v.w;
    Bs[bk][be + 8] = b2v.x;  Bs[bk][be + 9] = b2v.y;  Bs[bk][be + 10] = b2v.z; Bs[bk][be + 11] = b2v.w;
    Bs[bk][be + 12] = b3v.x; Bs[bk][be + 13] = b3v.y; Bs[bk][be + 14] = b3v.z; Bs[bk][be + 15] = b3v.w;
    __syncthreads();
    #pragma unroll
    for (int kk = 0; kk < 32; kk++) {
      float a0 = As[kk][t0 + 0], a1 = As[kk][t0 + 1], a2 = As[kk][t0 + 2], a3 = As[kk][t0 + 3];
      float b0 = Bs[kk][e0 + 0], b1 = Bs[kk][e0 + 1], b2 = Bs[kk][e0 + 2], b3 = Bs[kk][e0 + 3];
      acc[0][0] += a0 * b0; acc[0][1] += a0 * b1; acc[0][2] += a0 * b2; acc[0][3] += a0 * b3;
      acc[1][0] += a1 * b0; acc[1][1] += a1 * b1; acc[1][2] += a1 * b2; acc[1][3] += a1 * b3;
      acc[2][0] += a2 * b0; acc[2][1] += a2 * b1; acc[2][2] += a2 * b2; acc[2][3] += a2 * b3;
      acc[3][0] += a3 * b0; acc[3][1] += a3 * b1; acc[3][2] += a3 * b2; acc[3][3] += a3 * b3;
    }
    __syncthreads();
  }
  #pragma unroll
  for (int i = 0; i < 4; i++) {
    float* cp = C + (size_t)(row0 + t0 + i) * 128 + e0;
    #pragma unroll
    for (int j = 0; j < 4; j++) cp[j] = acc[i][j] + bias[e0 + j];
  }
}

// ---------------------------------------------------------------- GEMM + residual + LayerNorm (N=128 fixed)
// out[r,:] = LN(A@B + bias + res[r,:]) * g + bb. One 32-row tile per block; row stats via shfl.
__global__ __launch_bounds__(256) void gemm_ln_k(
    const float* __restrict__ A, const float* __restrict__ B,
    const float* __restrict__ bias, const float* __restrict__ res,
    const float* __restrict__ g, const float* __restrict__ bb,
    float* __restrict__ C, int K)
{
  __shared__ float As[32][36];
  __shared__ float Bs[32][136];
  const int tid = threadIdx.x;
  const int row0 = blockIdx.x * 32;
  const int tn = tid & 31, tm = tid >> 5;
  const int e0 = 4 * tn, t0 = 4 * tm;
  const int ar = tid >> 3, ak = (tid & 7) * 4;
  const int bk = tid >> 3, be = (tid & 7) * 16;
  float acc[4][4] = {};
  for (int k0 = 0; k0 < K; k0 += 32) {
    float4 av = *(const float4*)(A + (size_t)(row0 + ar) * K + k0 + ak);
    As[ak + 0][ar] = av.x; As[ak + 1][ar] = av.y; As[ak + 2][ar] = av.z; As[ak + 3][ar] = av.w;
    const float* bp = B + (size_t)(k0 + bk) * 128 + be;
    float4 b0v = *(const float4*)(bp + 0);
    float4 b1v = *(const float4*)(bp + 4);
    float4 b2v = *(const float4*)(bp + 8);
    float4 b3v = *(const float4*)(bp + 12);
    Bs[bk][be + 0] = b0v.x;  Bs[bk][be + 1] = b0v.y;  Bs[bk][be + 2] = b0v.z;  Bs[bk][be + 3] = b0v.w;
    Bs[bk][be + 4] = b1v.x;  Bs[bk][be + 5] = b1v.y;  Bs[bk][be + 6] = b1v.z;  Bs[bk][be + 7] = b1v.w;
    Bs[bk][be + 8] = b2v.x;  Bs[bk][be + 9] = b2v.y;  Bs[bk][be + 10] = b2v.z; Bs[bk][be + 11] = b2v.w;
    Bs[bk][be + 12] = b3v.x; Bs[bk][be + 13] = b3v.y; Bs[bk][be + 14] = b3v.z; Bs[bk][be + 15] = b3v.w;
    __syncthreads();
    #pragma unroll
    for (int kk = 0; kk < 32; kk++) {
      float a0 = As[kk][t0 + 0], a1 = As[kk][t0 + 1], a2 = As[kk][t0 + 2], a3 = As[kk][t0 + 3];
      float b0 = Bs[kk][e0 + 0], b1 = Bs[kk][e0 + 1], b2 = Bs[kk][e0 + 2], b3 = Bs[kk][e0 + 3];
      acc[0][0] += a0 * b0; acc[0][1] += a0 * b1; acc[0][2] += a0 * b2; acc[0][3] += a0 * b3;
      acc[1][0] += a1 * b0; acc[1][1] += a1 * b1; acc[1][2] += a1 * b2; acc[1][3] += a1 * b3;
      acc[2][0] += a2 * b0; acc[2][1] += a2 * b1; acc[2][2] += a2 * b2; acc[2][3] += a2 * b3;
      acc[3][0] += a3 * b0; acc[3][1] += a3 * b1; acc[3][2] += a3 * b2; acc[3][3] += a3 * b3;
    }
    __syncthreads();
  }
  // epilogue: +bias +res, then per-row LN across the 32 threads sharing tm (lanes closed under xor<32)
  #pragma unroll
  for (int i = 0; i < 4; i++) {
    int r = row0 + t0 + i;
    float v0 = acc[i][0] + bias[e0 + 0] + res[(size_t)r * 128 + e0 + 0];
    float v1 = acc[i][1] + bias[e0 + 1] + res[(size_t)r * 128 + e0 + 1];
    float v2 = acc[i][2] + bias[e0 + 2] + res[(size_t)r * 128 + e0 + 2];
    float v3 = acc[i][3] + bias[e0 + 3] + res[(size_t)r * 128 + e0 + 3];
    float s = v0 + v1 + v2 + v3;
    #pragma unroll
    for (int o = 1; o < 32; o <<= 1) s += __shfl_xor(s, o);
    float mean = s * (1.0f / 128.0f);
    float d0 = v0 - mean, d1 = v1 - mean, d2 = v2 - mean, d3 = v3 - mean;
    float sq = d0 * d0 + d1 * d1 + d2 * d2 + d3 * d3;
    #pragma unroll
    for (int o = 1; o < 32; o <<= 1) sq += __shfl_xor(sq, o);
    float rstd = 1.0f / sqrtf(sq * (1.0f / 128.0f) + 1e-5f);
    float* cp = C + (size_t)r * 128 + e0;
    cp[0] = d0 * rstd * g[e0 + 0] + bb[e0 + 0];
    cp[1] = d1 * rstd * g[e0 + 1] + bb[e0 + 1];
    cp[2] = d2 * rstd * g[e0 + 2] + bb[e0 + 2];
    cp[3] = d3 * rstd * g[e0 + 3] + bb[e0 + 3];
  }
}

// ---------------------------------------------------------------- LayerNorm rows of 128 (used once after edge aggr)
__global__ __launch_bounds__(128) void ln_k(
    const float* __restrict__ x, const float* __restrict__ res,
    const float* __restrict__ g, const float* __restrict__ b, float* __restrict__ out)
{
  __shared__ float sred[2];
  int r = blockIdx.x, e = threadIdx.x;
  size_t idx = (size_t)r * 128 + e;
  float v = x[idx] + res[idx];
  float nv = blk_norm(v, e, sred);
  out[idx] = nv * g[e] + b[e];
}

// ---------------------------------------------------------------- graph attention (N=32, GD=16) per (g,h)
__global__ __launch_bounds__(256) void gattn_k(
    const float* __restrict__ q, const float* __restrict__ k, const float* __restrict__ v,
    const float* __restrict__ dist, float* __restrict__ o)
{
  __shared__ float qs[32][17], ksh[32][17], vsh[32][17], ss[32][33], rs[32];
  const int g = blockIdx.x, h = blockIdx.y, tid = threadIdx.x;
  {
    int idx = tid * 2;
    int i = idx >> 4, d = idx & 15;
    size_t base = ((size_t)(g * 32 + i)) * 128 + h * 16 + d;
    qs[i][d] = q[base];  qs[i][d + 1] = q[base + 1];
    ksh[i][d] = k[base]; ksh[i][d + 1] = k[base + 1];
    vsh[i][d] = v[base]; vsh[i][d + 1] = v[base + 1];
  }
  __syncthreads();
  {
    int i = tid >> 3, j0 = (tid & 7) * 4;
    for (int j = j0; j < j0 + 4; j++) {
      float a = 0;
      #pragma unroll
      for (int d = 0; d < 16; d++) a += qs[i][d] * ksh[j][d];
      a = a * 0.25f + dist[(size_t)g * 1024 + i * 32 + j];
      ss[i][j] = fminf(fmaxf(a, -10.0f), 10.0f);
    }
  }
  __syncthreads();
  if (tid < 32) {
    float m = -1e30f;
    for (int j = 0; j < 32; j++) m = fmaxf(m, ss[tid][j]);
    float sm = 0;
    for (int j = 0; j < 32; j++) { float ex = expf(ss[tid][j] - m); ss[tid][j] = ex; sm += ex; }
    rs[tid] = 1.0f / sm;
  }
  __syncthreads();
  {
    int idx = tid * 2;
    int i = idx >> 4, d = idx & 15;
    float a0 = 0, a1 = 0;
    for (int j = 0; j < 32; j++) { float wj = ss[i][j]; a0 += wj * vsh[j][d]; a1 += wj * vsh[j][d + 1]; }
    float r = rs[i];
    size_t base = ((size_t)(g * 32 + i)) * 128 + h * 16 + d;
    o[base] = a0 * r; o[base + 1] = a1 * r;
  }
}

// ---------------------------------------------------------------- sequence attention (L=128, SD=32) per (b,h,qtile)
__global__ __launch_bounds__(256) void sattn_k(const float* __restrict__ qkv, float* __restrict__ o)
{
  __shared__ float ks[128][33];
  __shared__ float vs[128][33];
  __shared__ float qs[32][33];
  __shared__ float ss[32][129];
  __shared__ float red[32][8];
  __shared__ float red2[32][8];
  const int b = blockIdx.x, h = blockIdx.y, qt = blockIdx.z, tid = threadIdx.x;
  {
    int l = tid >> 1, d0 = (tid & 1) * 16;
    const float* kp = qkv + ((size_t)(b * 128 + l)) * 384 + 128 + h * 32 + d0;
    #pragma unroll
    for (int j = 0; j < 16; j++) { ks[l][d0 + j] = kp[j]; vs[l][d0 + j] = kp[128 + j]; }
  }
  {
    int i = tid >> 3, d0 = (tid & 7) * 4;
    const float* qp = qkv + ((size_t)(b * 128 + qt * 32 + i)) * 384 + h * 32 + d0;
    #pragma unroll
    for (int j = 0; j < 4; j++) qs[i][d0 + j] = qp[j];
  }
  __syncthreads();
  const int i = tid >> 3, sub = tid & 7;
  {
    int j0 = sub * 16;
    for (int j = j0; j < j0 + 16; j++) {
      float a = 0;
      #pragma unroll
      for (int d = 0; d < 32; d++) a += qs[i][d] * ks[j][d];
      ss[i][j] = a * 0.17677669529663687f;   // 1/sqrt(32)
    }
  }
  __syncthreads();
  float m = -1e30f;
  for (int j = sub; j < 128; j += 8) m = fmaxf(m, ss[i][j]);
  red[i][sub] = m;
  __syncthreads();
  float mm = red[i][0];
  #pragma unroll
  for (int t = 1; t < 8; t++) mm = fmaxf(mm, red[i][t]);
  float ps = 0;
  for (int j = sub; j < 128; j += 8) { float ex = expf(ss[i][j] - mm); ss[i][j] = ex; ps += ex; }
  red2[i][sub] = ps;
  __syncthreads();
  float sm = 0;
  #pragma unroll
  for (int t = 0; t < 8; t++) sm += red2[i][t];
  float rinv = 1.0f / sm;
  {
    int d0 = sub * 4;
    float a0 = 0, a1 = 0, a2 = 0, a3 = 0;
    for (int j = 0; j < 128; j++) {
      float wj = ss[i][j];
      a0 += wj * vs[j][d0 + 0]; a1 += wj * vs[j][d0 + 1];
      a2 += wj * vs[j][d0 + 2]; a3 += wj * vs[j][d0 + 3];
    }
    float* op = o + ((size_t)(b * 128 + qt * 32 + i)) * 128 + h * 32 + d0;
    op[0] = a0 * rinv; op[1] = a1 * rinv; op[2] = a2 * rinv; op[3] = a3 * rinv;
  }
}

// ---------------------------------------------------------------- embedding
__global__ __launch_bounds__(128) void embed_k(
    const int* __restrict__ tokens, const float* __restrict__ tok_emb,
    const float* __restrict__ pos_emb, float* __restrict__ xs)
{
  int r = blockIdx.x, e = threadIdx.x;
  int tk = tokens[r];
  xs[(size_t)r * 128 + e] = tok_emb[(size_t)tk * 128 + e] + pos_emb[(size_t)(r & 127) * 128 + e];
}

// ---------------------------------------------------------------- pool + smean + fusion gate + cross-modal + head
__global__ __launch_bounds__(128) void head_k(
    const float* __restrict__ hb, const float* __restrict__ xs, const float* __restrict__ gfeat,
    const float* fg1w, const float* fg1b, const float* fg2w, const float* fg2b,
    const float* g2s_vw, const float* g2s_vb, const float* g2s_ow, const float* g2s_ob,
    const float* n1g, const float* n1b,
    const float* s2g_vw, const float* s2g_vb, const float* s2g_ow, const float* s2g_ob,
    const float* n2g, const float* n2b,
    const float* r1w, const float* r1b, const float* r2w, const float* r2b,
    float* __restrict__ out)
{
  __shared__ float T[128], S[128], G[128], Sm[128], t1[128], t2[128], gh[64], sred[2];
  int mol = blockIdx.x, e = threadIdx.x;
  {
    float cs = 0;
    for (int c = 0; c < 4; c++) {
      int g = mol * 4 + c;
      float s = 0;
      for (int i = 0; i < 32; i++) s += hb[((size_t)(g * 32 + i)) * 128 + e];
      cs += s * (1.0f / 32.0f);
    }
    cs *= 0.25f;
    float s2 = 0;
    int g = 64 + mol;
    for (int i = 0; i < 32; i++) s2 += hb[((size_t)(g * 32 + i)) * 128 + e];
    T[e] = cs + s2 * (1.0f / 32.0f);
    float ss = 0;
    for (int l = 0; l < 128; l++) ss += xs[((size_t)(mol * 128 + l)) * 128 + e];
    S[e] = ss * (1.0f / 128.0f);
  }
  __syncthreads();
  if (e < 64) {
    float a = fg1b[e];
    for (int f = 0; f < 128; f++) a += T[f] * fg1w[f * 64 + e];
    for (int f = 0; f < 128; f++) a += S[f] * fg1w[(128 + f) * 64 + e];
    gh[e] = fmaxf(a, 0.0f);
  }
  __syncthreads();
  {
    float a = fg2b[e];
    for (int j = 0; j < 64; j++) a += gh[j] * fg2w[j * 128 + e];
    float gate = 1.0f / (1.0f + expf(-a));
    float fu = gate * T[e] + (1.0f - gate) * S[e];
    G[e] = fu; Sm[e] = fu;
  }
  __syncthreads();
  for (int l = 0; l < 2; l++) {
    const float* vw = g2s_vw + (size_t)l * 16384; const float* vb = g2s_vb + l * 128;
    const float* ow = g2s_ow + (size_t)l * 16384; const float* ob = g2s_ob + l * 128;
    float a = vb[e];
    for (int f = 0; f < 128; f++) a += Sm[f] * vw[f * 128 + e];
    t1[e] = a;
    __syncthreads();
    a = ob[e];
    for (int f = 0; f < 128; f++) a += t1[f] * ow[f * 128 + e];
    float nv = blk_norm(G[e] + a, e, sred);
    G[e] = nv * n1g[l * 128 + e] + n1b[l * 128 + e];
    __syncthreads();
    const float* vw2 = s2g_vw + (size_t)l * 16384; const float* vb2 = s2g_vb + l * 128;
    const float* ow2 = s2g_ow + (size_t)l * 16384; const float* ob2 = s2g_ob + l * 128;
    a = vb2[e];
    for (int f = 0; f < 128; f++) a += G[f] * vw2[f * 128 + e];
    t1[e] = a;
    __syncthreads();
    a = ob2[e];
    for (int f = 0; f < 128; f++) a += t1[f] * ow2[f * 128 + e];
    nv = blk_norm(Sm[e] + a, e, sred);
    Sm[e] = nv * n2g[l * 128 + e] + n2b[l * 128 + e];
    __syncthreads();
  }
  t2[e] = 0.5f * (G[e] + Sm[e]);
  __syncthreads();
  float a = r1b[e];
  for (int f = 0; f < 128; f++) a += t2[f] * r1w[f * 128 + e];
  for (int f = 0; f < 3; f++) a += gfeat[mol * 3 + f] * r1w[(128 + f) * 128 + e];
  a = fmaxf(a, 0.0f);
  float p = a * r2w[e];
  #pragma unroll
  for (int o = 1; o < 64; o <<= 1) p += __shfl_xor(p, o);
  if ((e & 63) == 0) sred[e >> 6] = p;
  __syncthreads();
  if (e == 0) {
    float result = sred[0] + sred[1] + r2b[0];
    if (!isfinite(result)) {
      float flag = 0.0f;
      if (!isfinite(hb[mol])) flag += 1.0f;
      if (!isfinite(xs[mol])) flag += 2.0f;
      if (!isfinite(T[0])) flag += 4.0f;
      if (!isfinite(S[0])) flag += 8.0f;
      result = 512.0f + flag;
    }
    out[mol] = result;
  }
}

// ================================================================ host
extern "C" void kernel_launch(void* const* d_in, const int* in_sizes, int n_in,
                              void* d_out, int out_size, void* d_ws, size_t ws_size,
                              hipStream_t stream)
{
  (void)n_in; (void)out_size; (void)ws_size;
  const bool dict = (in_sizes[1] == 8192);
  auto IN = [&](int di, int si) { return d_in[dict ? di : si]; };

  const float* conf_x   = (const float*)IN(0, 0);
  const int*   conf_ei  = (const int*)  IN(1, 63);
  const float* conf_ea  = (const float*)IN(2, 1);
  const float* conf_pos = (const float*)IN(3, 2);
  const float* scaf_x   = (const float*)IN(4, 3);
  const int*   scaf_ei  = (const int*)  IN(5, 64);
  const float* scaf_ea  = (const float*)IN(6, 4);
  const float* scaf_pos = (const float*)IN(7, 5);
  const int*   tokens   = (const int*)  IN(8, 65);
  const float* gfeat    = (const float*)IN(9, 6);
  const float* gproj_w  = (const float*)IN(11, 7);
  const float* gproj_b  = (const float*)IN(12, 8);
  const float* elin_w   = (const float*)IN(13, 9);
  const float* elin_b   = (const float*)IN(14, 10);
  const float* eln_g    = (const float*)IN(15, 11);
  const float* eln_b    = (const float*)IN(16, 12);
  const float* gt_qw    = (const float*)IN(17, 13);
  const float* gt_qb    = (const float*)IN(18, 14);
  const float* gt_kw    = (const float*)IN(19, 15);
  const float* gt_kb    = (const float*)IN(20, 16);
  const float* gt_vw    = (const float*)IN(21, 17);
  const float* gt_vb    = (const float*)IN(22, 18);
  const float* gt_ow    = (const float*)IN(23, 19);
  const float* gt_ob    = (const float*)IN(24, 20);
  const float* gt_ln1g  = (const float*)IN(25, 21);
  const float* gt_ln1b  = (const float*)IN(26, 22);
  const float* gt_f1w   = (const float*)IN(27, 23);
  const float* gt_f1b   = (const float*)IN(28, 24);
  const float* gt_f2w   = (const float*)IN(29, 25);
  const float* gt_f2b   = (const float*)IN(30, 26);
  const float* gt_ln2g  = (const float*)IN(31, 27);
  const float* gt_ln2b  = (const float*)IN(32, 28);
  const float* tok_emb  = (const float*)IN(33, 29);
  const float* pos_emb  = (const float*)IN(34, 30);
  const float* se_inw   = (const float*)IN(35, 31);
  const float* se_inb   = (const float*)IN(36, 32);
  const float* se_ow    = (const float*)IN(37, 33);
  const float* se_ob    = (const float*)IN(38, 34);
  const float* se_ln1g  = (const float*)IN(39, 35);
  const float* se_ln1b  = (const float*)IN(40, 36);
  const float* se_f1w   = (const float*)IN(41, 37);
  const float* se_f1b   = (const float*)IN(42, 38);
  const float* se_f2w   = (const float*)IN(43, 39);
  const float* se_f2b   = (const float*)IN(44, 40);
  const float* se_ln2g  = (const float*)IN(45, 41);
  const float* se_ln2b  = (const float*)IN(46, 42);
  const float* fg1_w    = (const float*)IN(47, 43);
  const float* fg1_b    = (const float*)IN(48, 44);
  const float* fg2_w    = (const float*)IN(49, 45);
  const float* fg2_b    = (const float*)IN(50, 46);
  const float* cm_g2s_vw = (const float*)IN(51, 47);
  const float* cm_g2s_vb = (const float*)IN(52, 48);
  const float* cm_g2s_ow = (const float*)IN(53, 49);
  const float* cm_g2s_ob = (const float*)IN(54, 50);
  const float* cm_s2g_vw = (const float*)IN(55, 53);
  const float* cm_s2g_vb = (const float*)IN(56, 54);
  const float* cm_s2g_ow = (const float*)IN(57, 55);
  const float* cm_s2g_ob = (const float*)IN(58, 56);
  const float* cm_n1g   = (const float*)IN(59, 51);
  const float* cm_n1b   = (const float*)IN(60, 52);
  const float* cm_n2g   = (const float*)IN(61, 57);
  const float* cm_n2b   = (const float*)IN(62, 58);
  const float* r1_w     = (const float*)IN(63, 59);
  const float* r1_b     = (const float*)IN(64, 60);
  const float* r2_w     = (const float*)IN(65, 61);
  const float* r2_b     = (const float*)IN(66, 62);
  float* out = (float*)d_out;

  // ---- workspace (fp32) ----
  float* w = (float*)d_ws;
  size_t off = 0;
  auto alloc = [&](size_t n) { float* p = w + off; off += n; return p; };
  float* h     = alloc(2560 * 128);
  float* aggr  = alloc(2560 * 128);
  float* hb    = alloc(2560 * 128);
  float* distb = alloc(80 * 1024);
  float* gtmp  = alloc(2949120);
  float* xsfin = alloc(2048 * 128);
  // graph-layer carve
  float* qb    = gtmp;                  // q/k/v contiguous, stride 327680
  float* atto  = gtmp + 983040;
  float* x1b   = gtmp + 1310720;
  float* ffh   = gtmp + 1638400;        // 2560*256
  // seq carve
  float* xs2    = gtmp;                 // 2048*128
  float* qkv3   = gtmp + 262144;        // 2048*384
  float* satto  = gtmp + 1048576;
  float* sx1    = gtmp + 1310720;
  float* sffh   = gtmp + 1572864;       // 2048*256

  // ============ graph encoder ============
  node_proj_k<<<2560, 128, 0, stream>>>(conf_x, scaf_x, gproj_w, gproj_b, h);
  dist_k<<<80, 256, 0, stream>>>(conf_pos, scaf_pos, distb);
  zero_k<<<1280, 256, 0, stream>>>(aggr, 2560 * 128);
  edge_gemm_k<<<dim3(160, 8), 256, 0, stream>>>(conf_ea, scaf_ea, conf_ei, scaf_ei, h, elin_w, elin_b, aggr);
  ln_k<<<2560, 128, 0, stream>>>(aggr, h, eln_g, eln_b, hb);

  for (int l = 0; l < 3; l++) {
    gemm3_k<<<dim3(3, 80), 256, 0, stream>>>(hb,
        gt_qw + (size_t)l * 16384, gt_kw + (size_t)l * 16384, gt_vw + (size_t)l * 16384,
        gt_qb + l * 128, gt_kb + l * 128, gt_vb + l * 128, qb, 327680);
    gattn_k<<<dim3(80, 8), 256, 0, stream>>>(qb, qb + 327680, qb + 655360, distb, atto);
    gemm_ln_k<<<80, 256, 0, stream>>>(atto, gt_ow + (size_t)l * 16384, gt_ob + l * 128,
                                      hb, gt_ln1g + l * 128, gt_ln1b + l * 128, x1b, 128);
    gemm_k<<<dim3(2, 80), 256, 0, stream>>>(x1b, gt_f1w + (size_t)l * 32768, gt_f1b + l * 256, ffh, 128, 256, 1);
    gemm_ln_k<<<80, 256, 0, stream>>>(ffh, gt_f2w + (size_t)l * 32768, gt_f2b + l * 128,
                                      x1b, gt_ln2g + l * 128, gt_ln2b + l * 128, hb, 256);
  }

  // ============ sequence encoder ============
  embed_k<<<2048, 128, 0, stream>>>(tokens, tok_emb, pos_emb, xs2);
  for (int l = 0; l < 4; l++) {
    gemm_k<<<dim3(3, 64), 256, 0, stream>>>(xs2, se_inw + (size_t)l * 49152, se_inb + l * 384, qkv3, 128, 384, 0);
    sattn_k<<<dim3(16, 4, 4), 256, 0, stream>>>(qkv3, satto);
    gemm_ln_k<<<64, 256, 0, stream>>>(satto, se_ow + (size_t)l * 16384, se_ob + l * 128,
                                      xs2, se_ln1g + l * 128, se_ln1b + l * 128, sx1, 128);
    gemm_k<<<dim3(2, 64), 256, 0, stream>>>(sx1, se_f1w + (size_t)l * 32768, se_f1b + l * 256, sffh, 128, 256, 1);
    gemm_ln_k<<<64, 256, 0, stream>>>(sffh, se_f2w + (size_t)l * 32768, se_f2b + l * 128,
                                      sx1, se_ln2g + l * 128, se_ln2b + l * 128,
                                      (l == 3) ? xsfin : xs2, 256);
  }

  // ============ pool + smean + fusion + cross-modal + regressor ============
  head_k<<<16, 128, 0, stream>>>(hb, xsfin, gfeat,
                                 fg1_w, fg1_b, fg2_w, fg2_b,
                                 cm_g2s_vw, cm_g2s_vb, cm_g2s_ow, cm_g2s_ob, cm_n1g, cm_n1b,
                                 cm_s2g_vw, cm_s2g_vb, cm_s2g_ow, cm_s2g_ob, cm_n2g, cm_n2b,
                                 r1_w, r1_b, r2_w, r2_b, out);
}

// Round 6
// 764.955 us; speedup vs baseline: 1.3296x; 1.1136x over previous
//
#include <hip/hip_runtime.h>
#include <hip/hip_bf16.h>

// E=128 GH=8 GD=16 GL=3 | SH=4 SD=32 SL=4 | N=32 GC=64 GS=16 DEG=64 BMOL=16
// M_conf=4096 M_scaf=1024 M_tot=5120. All float tensors fp32.

// ---------------------------------------------------------------- LN helper (block of 128 threads)
__device__ __forceinline__ float blk_norm(float v, int e, float* sred)
{
  float s = v;
  #pragma unroll
  for (int o = 1; o < 64; o <<= 1) s += __shfl_xor(s, o);
  if ((e & 63) == 0) sred[e >> 6] = s;
  __syncthreads();
  float mean = (sred[0] + sred[1]) * (1.0f / 128.0f);
  __syncthreads();
  float d = v - mean;
  float s2 = d * d;
  #pragma unroll
  for (int o = 1; o < 64; o <<= 1) s2 += __shfl_xor(s2, o);
  if ((e & 63) == 0) sred[e >> 6] = s2;
  __syncthreads();
  float var = (sred[0] + sred[1]) * (1.0f / 128.0f);
  __syncthreads();
  return d / sqrtf(var + 1e-5f);
}

// ---------------------------------------------------------------- node projection (+ zero aggr)
__global__ __launch_bounds__(128) void node_proj_k(
    const float* __restrict__ cx, const float* __restrict__ sx,
    const float* __restrict__ w, const float* __restrict__ b,
    float* __restrict__ h, float* __restrict__ aggr)
{
  int r = blockIdx.x, e = threadIdx.x;
  const float* x = (r < 2048) ? (cx + (size_t)r * 64) : (sx + (size_t)(r - 2048) * 64);
  __shared__ float xs[64];
  if (e < 64) xs[e] = x[e];
  __syncthreads();
  float acc = b[e];
  for (int a = 0; a < 64; a++) acc += xs[a] * w[a * 128 + e];
  h[(size_t)r * 128 + e] = acc;
  aggr[(size_t)r * 128 + e] = 0.0f;
}

// ---------------------------------------------------------------- pairwise distance per graph
__global__ __launch_bounds__(256) void dist_k(
    const float* __restrict__ cpos, const float* __restrict__ spos, float* __restrict__ dist)
{
  int g = blockIdx.x, tid = threadIdx.x;
  __shared__ float P[96];
  const float* p = (g < 64) ? (cpos + (size_t)g * 96) : (spos + (size_t)(g - 64) * 96);
  if (tid < 96) P[tid] = p[tid];
  __syncthreads();
  #pragma unroll
  for (int jj = 0; jj < 4; jj++) {
    int idx = tid * 4 + jj;
    int i = idx >> 5, j = idx & 31;
    float dx = P[i * 3 + 0] - P[j * 3 + 0];
    float dy = P[i * 3 + 1] - P[j * 3 + 1];
    float dz = P[i * 3 + 2] - P[j * 3 + 2];
    float d2 = dx * dx + dy * dy + dz * dz;
    dist[(size_t)g * 1024 + idx] = (d2 > 0.0f) ? sqrtf(d2) : 0.0f;
  }
}

// ---------------------------------------------------------------- EdgeNetwork GEMM + atomic scatter
// grid (160, 14): 32-edge tile x 14-kt chunk (kt=(c,fblock), 196 total; each chunk spans 4 c's).
__global__ __launch_bounds__(256) void edge_gemm_k(
    const float* __restrict__ cea, const float* __restrict__ sea,
    const int* __restrict__ cei, const int* __restrict__ sei,
    const float* __restrict__ h,
    const float* __restrict__ elw, const float* __restrict__ elb,
    float* __restrict__ aggr)
{
  __shared__ float efs[32][6];
  __shared__ float hds[32][128];
  __shared__ float As[32][36];     // 144B rows -> b128-aligned
  __shared__ float Bs[32][136];
  __shared__ int srcs[32], dsts[32];
  const int tid = threadIdx.x;
  const int m0 = blockIdx.x * 32;
  const int kt0 = blockIdx.y * 14;
  const int c0 = kt0 >> 2;
  if (tid < 32) {
    int m = m0 + tid;
    int src, dst;
    if (m < 4096) { src = cei[m]; dst = cei[4096 + m]; }
    else { src = sei[m - 4096] + 2048; dst = sei[1024 + (m - 4096)] + 2048; }
    srcs[tid] = src; dsts[tid] = dst;
  }
  __syncthreads();
  for (int i = tid; i < 4096; i += 256) {
    int t = i >> 7, f = i & 127;
    hds[t][f] = h[(size_t)dsts[t] * 128 + f];
  }
  if (tid < 128) {
    int t = tid >> 2, cc = tid & 3;
    int c = c0 + cc;
    int m = m0 + t;
    const float* attr = (m < 4096) ? (cea + (size_t)m * 17) : (sea + (size_t)(m - 4096) * 17);
    float val;
    if (c < 16) val = attr[c];
    else if (c < 48) {
      float d = fminf(fmaxf(attr[16], 0.0f), 10.0f);
      float t2 = d - (float)((c - 16) * (5.0 / 31.0));
      val = expf(-38.44f * t2 * t2);
    } else val = 1.0f;
    efs[t][cc] = val;
  }
  const int tn = tid & 31, tm = tid >> 5;
  const int e0 = 4 * tn, t0 = 4 * tm;
  const int gk = tid & 31;          // As gen: k lane
  const int gt = (tid >> 5) * 4;    // As gen: edge offset
  const int se = tid >> 1;          // Bs stage: e
  const int sk = (tid & 1) * 16;    // Bs stage: k offset
  float acc[4][4] = {};
  __syncthreads();
  #pragma unroll 1
  for (int kt = kt0; kt < kt0 + 14; kt++) {
    int c = kt >> 2, cc = c - c0, f0 = (kt & 3) * 32;
    float4 av;
    av.x = efs[gt + 0][cc] * hds[gt + 0][f0 + gk];
    av.y = efs[gt + 1][cc] * hds[gt + 1][f0 + gk];
    av.z = efs[gt + 2][cc] * hds[gt + 2][f0 + gk];
    av.w = efs[gt + 3][cc] * hds[gt + 3][f0 + gk];
    *(float4*)&As[gk][gt] = av;
    const float* bp = ((c < 48) ? (elw + (size_t)c * 16384) : elb) + (size_t)se * 128 + f0 + sk;
    float4 w0 = *(const float4*)(bp + 0);
    float4 w1 = *(const float4*)(bp + 4);
    float4 w2 = *(const float4*)(bp + 8);
    float4 w3 = *(const float4*)(bp + 12);
    Bs[sk + 0][se] = w0.x;  Bs[sk + 1][se] = w0.y;  Bs[sk + 2][se] = w0.z;  Bs[sk + 3][se] = w0.w;
    Bs[sk + 4][se] = w1.x;  Bs[sk + 5][se] = w1.y;  Bs[sk + 6][se] = w1.z;  Bs[sk + 7][se] = w1.w;
    Bs[sk + 8][se] = w2.x;  Bs[sk + 9][se] = w2.y;  Bs[sk + 10][se] = w2.z; Bs[sk + 11][se] = w2.w;
    Bs[sk + 12][se] = w3.x; Bs[sk + 13][se] = w3.y; Bs[sk + 14][se] = w3.z; Bs[sk + 15][se] = w3.w;
    __syncthreads();
    #pragma unroll
    for (int kk = 0; kk < 32; kk++) {
      float4 a = *(const float4*)&As[kk][t0];
      float4 b = *(const float4*)&Bs[kk][e0];
      acc[0][0] += a.x * b.x; acc[0][1] += a.x * b.y; acc[0][2] += a.x * b.z; acc[0][3] += a.x * b.w;
      acc[1][0] += a.y * b.x; acc[1][1] += a.y * b.y; acc[1][2] += a.y * b.z; acc[1][3] += a.y * b.w;
      acc[2][0] += a.z * b.x; acc[2][1] += a.z * b.y; acc[2][2] += a.z * b.z; acc[2][3] += a.z * b.w;
      acc[3][0] += a.w * b.x; acc[3][1] += a.w * b.y; acc[3][2] += a.w * b.z; acc[3][3] += a.w * b.w;
    }
    __syncthreads();
  }
  #pragma unroll
  for (int i = 0; i < 4; i++) {
    float* dst = aggr + (size_t)srcs[t0 + i] * 128 + e0;
    atomicAdd(dst + 0, acc[i][0]);
    atomicAdd(dst + 1, acc[i][1]);
    atomicAdd(dst + 2, acc[i][2]);
    atomicAdd(dst + 3, acc[i][3]);
  }
}

// ---------------------------------------------------------------- BM=16 GEMM: C = A[M,K]@B[K,N] + bias
// grid (N/128, M/16). 256 thr, micro 2x4.
__global__ __launch_bounds__(256) void gemm16_k(
    const float* __restrict__ A, const float* __restrict__ B,
    const float* __restrict__ bias, float* __restrict__ C,
    int K, int N)
{
  __shared__ float Sa[32][20];
  __shared__ float Bs[32][136];
  const int tid = threadIdx.x;
  const int row0 = blockIdx.y * 16;
  const int n0 = blockIdx.x * 128;
  const int tm = tid >> 5, tn = tid & 31;
  const int t0 = 2 * tm, e0 = 4 * tn;
  const int ar = tid >> 4, ak = (tid & 15) * 2;
  const int bk = tid >> 3, be = (tid & 7) * 16;
  float acc[2][4] = {};
  for (int k0 = 0; k0 < K; k0 += 32) {
    float2 av = *(const float2*)(A + (size_t)(row0 + ar) * K + k0 + ak);
    Sa[ak][ar] = av.x; Sa[ak + 1][ar] = av.y;
    const float* bp = B + (size_t)(k0 + bk) * N + n0 + be;
    float4 b0v = *(const float4*)(bp + 0);
    float4 b1v = *(const float4*)(bp + 4);
    float4 b2v = *(const float4*)(bp + 8);
    float4 b3v = *(const float4*)(bp + 12);
    Bs[bk][be + 0] = b0v.x;  Bs[bk][be + 1] = b0v.y;  Bs[bk][be + 2] = b0v.z;  Bs[bk][be + 3] = b0v.w;
    Bs[bk][be + 4] = b1v.x;  Bs[bk][be + 5] = b1v.y;  Bs[bk][be + 6] = b1v.z;  Bs[bk][be + 7] = b1v.w;
    Bs[bk][be + 8] = b2v.x;  Bs[bk][be + 9] = b2v.y;  Bs[bk][be + 10] = b2v.z; Bs[bk][be + 11] = b2v.w;
    Bs[bk][be + 12] = b3v.x; Bs[bk][be + 13] = b3v.y; Bs[bk][be + 14] = b3v.z; Bs[bk][be + 15] = b3v.w;
    __syncthreads();
    #pragma unroll
    for (int kk = 0; kk < 32; kk++) {
      float2 a = *(const float2*)&Sa[kk][t0];
      float4 b = *(const float4*)&Bs[kk][e0];
      acc[0][0] += a.x * b.x; acc[0][1] += a.x * b.y; acc[0][2] += a.x * b.z; acc[0][3] += a.x * b.w;
      acc[1][0] += a.y * b.x; acc[1][1] += a.y * b.y; acc[1][2] += a.y * b.z; acc[1][3] += a.y * b.w;
    }
    __syncthreads();
  }
  #pragma unroll
  for (int i = 0; i < 2; i++) {
    float* cp = C + (size_t)(row0 + t0 + i) * N + n0 + e0;
    #pragma unroll
    for (int j = 0; j < 4; j++) cp[j] = acc[i][j] + bias[n0 + e0 + j];
  }
}

// ---------------------------------------------------------------- fused QKV (graph): grid (3, 160)
__global__ __launch_bounds__(256) void gemm3_k(
    const float* __restrict__ A,
    const float* __restrict__ Bq, const float* __restrict__ Bk, const float* __restrict__ Bv,
    const float* __restrict__ bq, const float* __restrict__ bk_, const float* __restrict__ bv,
    float* __restrict__ Cbase, int cstride)
{
  const int z = blockIdx.x;
  const float* B = (z == 0) ? Bq : (z == 1) ? Bk : Bv;
  const float* bias = (z == 0) ? bq : (z == 1) ? bk_ : bv;
  float* C = Cbase + (size_t)z * cstride;
  __shared__ float Sa[32][20];
  __shared__ float Bs[32][136];
  const int tid = threadIdx.x;
  const int row0 = blockIdx.y * 16;
  const int tm = tid >> 5, tn = tid & 31;
  const int t0 = 2 * tm, e0 = 4 * tn;
  const int ar = tid >> 4, ak = (tid & 15) * 2;
  const int bk = tid >> 3, be = (tid & 7) * 16;
  float acc[2][4] = {};
  for (int k0 = 0; k0 < 128; k0 += 32) {
    float2 av = *(const float2*)(A + (size_t)(row0 + ar) * 128 + k0 + ak);
    Sa[ak][ar] = av.x; Sa[ak + 1][ar] = av.y;
    const float* bp = B + (size_t)(k0 + bk) * 128 + be;
    float4 b0v = *(const float4*)(bp + 0);
    float4 b1v = *(const float4*)(bp + 4);
    float4 b2v = *(const float4*)(bp + 8);
    float4 b3v = *(const float4*)(bp + 12);
    Bs[bk][be + 0] = b0v.x;  Bs[bk][be + 1] = b0v.y;  Bs[bk][be + 2] = b0v.z;  Bs[bk][be + 3] = b0v.w;
    Bs[bk][be + 4] = b1v.x;  Bs[bk][be + 5] = b1v.y;  Bs[bk][be + 6] = b1v.z;  Bs[bk][be + 7] = b1v.w;
    Bs[bk][be + 8] = b2v.x;  Bs[bk][be + 9] = b2v.y;  Bs[bk][be + 10] = b2v.z; Bs[bk][be + 11] = b2v.w;
    Bs[bk][be + 12] = b3v.x; Bs[bk][be + 13] = b3v.y; Bs[bk][be + 14] = b3v.z; Bs[bk][be + 15] = b3v.w;
    __syncthreads();
    #pragma unroll
    for (int kk = 0; kk < 32; kk++) {
      float2 a = *(const float2*)&Sa[kk][t0];
      float4 b = *(const float4*)&Bs[kk][e0];
      acc[0][0] += a.x * b.x; acc[0][1] += a.x * b.y; acc[0][2] += a.x * b.z; acc[0][3] += a.x * b.w;
      acc[1][0] += a.y * b.x; acc[1][1] += a.y * b.y; acc[1][2] += a.y * b.z; acc[1][3] += a.y * b.w;
    }
    __syncthreads();
  }
  #pragma unroll
  for (int i = 0; i < 2; i++) {
    float* cp = C + (size_t)(row0 + t0 + i) * 128 + e0;
    #pragma unroll
    for (int j = 0; j < 4; j++) cp[j] = acc[i][j] + bias[e0 + j];
  }
}

// ---------------------------------------------------------------- BM=16 GEMM + residual + LN (N=128)
__global__ __launch_bounds__(256) void gemm_ln_k(
    const float* __restrict__ A, const float* __restrict__ B,
    const float* __restrict__ bias, const float* __restrict__ res,
    const float* __restrict__ g, const float* __restrict__ bb,
    float* __restrict__ C, int K)
{
  __shared__ float Sa[32][20];
  __shared__ float Bs[32][136];
  const int tid = threadIdx.x;
  const int row0 = blockIdx.x * 16;
  const int tm = tid >> 5, tn = tid & 31;
  const int t0 = 2 * tm, e0 = 4 * tn;
  const int ar = tid >> 4, ak = (tid & 15) * 2;
  const int bk = tid >> 3, be = (tid & 7) * 16;
  float acc[2][4] = {};
  for (int k0 = 0; k0 < K; k0 += 32) {
    float2 av = *(const float2*)(A + (size_t)(row0 + ar) * K + k0 + ak);
    Sa[ak][ar] = av.x; Sa[ak + 1][ar] = av.y;
    const float* bp = B + (size_t)(k0 + bk) * 128 + be;
    float4 b0v = *(const float4*)(bp + 0);
    float4 b1v = *(const float4*)(bp + 4);
    float4 b2v = *(const float4*)(bp + 8);
    float4 b3v = *(const float4*)(bp + 12);
    Bs[bk][be + 0] = b0v.x;  Bs[bk][be + 1] = b0v.y;  Bs[bk][be + 2] = b0v.z;  Bs[bk][be + 3] = b0v.w;
    Bs[bk][be + 4] = b1v.x;  Bs[bk][be + 5] = b1v.y;  Bs[bk][be + 6] = b1v.z;  Bs[bk][be + 7] = b1v.w;
    Bs[bk][be + 8] = b2v.x;  Bs[bk][be + 9] = b2v.y;  Bs[bk][be + 10] = b2v.z; Bs[bk][be + 11] = b2v.w;
    Bs[bk][be + 12] = b3v.x; Bs[bk][be + 13] = b3v.y; Bs[bk][be + 14] = b3v.z; Bs[bk][be + 15] = b3v.w;
    __syncthreads();
    #pragma unroll
    for (int kk = 0; kk < 32; kk++) {
      float2 a = *(const float2*)&Sa[kk][t0];
      float4 b = *(const float4*)&Bs[kk][e0];
      acc[0][0] += a.x * b.x; acc[0][1] += a.x * b.y; acc[0][2] += a.x * b.z; acc[0][3] += a.x * b.w;
      acc[1][0] += a.y * b.x; acc[1][1] += a.y * b.y; acc[1][2] += a.y * b.z; acc[1][3] += a.y * b.w;
    }
    __syncthreads();
  }
  #pragma unroll
  for (int i = 0; i < 2; i++) {
    int r = row0 + t0 + i;
    float v0 = acc[i][0] + bias[e0 + 0] + res[(size_t)r * 128 + e0 + 0];
    float v1 = acc[i][1] + bias[e0 + 1] + res[(size_t)r * 128 + e0 + 1];
    float v2 = acc[i][2] + bias[e0 + 2] + res[(size_t)r * 128 + e0 + 2];
    float v3 = acc[i][3] + bias[e0 + 3] + res[(size_t)r * 128 + e0 + 3];
    float s = v0 + v1 + v2 + v3;
    #pragma unroll
    for (int o = 1; o < 32; o <<= 1) s += __shfl_xor(s, o);
    float mean = s * (1.0f / 128.0f);
    float d0 = v0 - mean, d1 = v1 - mean, d2 = v2 - mean, d3 = v3 - mean;
    float sq = d0 * d0 + d1 * d1 + d2 * d2 + d3 * d3;
    #pragma unroll
    for (int o = 1; o < 32; o <<= 1) sq += __shfl_xor(sq, o);
    float rstd = 1.0f / sqrtf(sq * (1.0f / 128.0f) + 1e-5f);
    float* cp = C + (size_t)r * 128 + e0;
    cp[0] = d0 * rstd * g[e0 + 0] + bb[e0 + 0];
    cp[1] = d1 * rstd * g[e0 + 1] + bb[e0 + 1];
    cp[2] = d2 * rstd * g[e0 + 2] + bb[e0 + 2];
    cp[3] = d3 * rstd * g[e0 + 3] + bb[e0 + 3];
  }
}

// ---------------------------------------------------------------- fused FFN: C = LN(relu(A@W1+b1)@W2+b2 + res)*g+bb
// A: M x 128, W1: 128x256, W2: 256x128. BM=16, grid M/16, 256 thr.
__global__ __launch_bounds__(256) void ffn_k(
    const float* __restrict__ A,
    const float* __restrict__ W1, const float* __restrict__ b1,
    const float* __restrict__ W2, const float* __restrict__ b2,
    const float* __restrict__ res, const float* __restrict__ g, const float* __restrict__ bb,
    float* __restrict__ C)
{
  __shared__ __align__(16) float hid[16][260];
  __shared__ __align__(16) float sb[4352];      // phase1: Bs1[16][260] (4160); phase2: Bs2[32][136] (4352)
  __shared__ __align__(16) float Sa[16][20];
  float (*Bs1)[260] = (float(*)[260])sb;
  float (*Bs2)[136] = (float(*)[136])sb;
  const int tid = threadIdx.x;
  const int row0 = blockIdx.x * 16;
  // ---- phase 1: hid = relu(A@W1 + b1), micro 4x4 over 16x256 ----
  {
    const int tm = tid >> 6, tn = tid & 63;
    const int t0 = 4 * tm, e0 = 4 * tn;
    const int ar = tid >> 4, ak = tid & 15;
    const int bk = tid >> 4, be = (tid & 15) * 16;
    float acc[4][4] = {};
    for (int k0 = 0; k0 < 128; k0 += 16) {
      Sa[ak][ar] = A[(size_t)(row0 + ar) * 128 + k0 + ak];
      const float* bp = W1 + (size_t)(k0 + bk) * 256 + be;
      float4 b0v = *(const float4*)(bp + 0);
      float4 b1v = *(const float4*)(bp + 4);
      float4 b2v = *(const float4*)(bp + 8);
      float4 b3v = *(const float4*)(bp + 12);
      Bs1[bk][be + 0] = b0v.x;  Bs1[bk][be + 1] = b0v.y;  Bs1[bk][be + 2] = b0v.z;  Bs1[bk][be + 3] = b0v.w;
      Bs1[bk][be + 4] = b1v.x;  Bs1[bk][be + 5] = b1v.y;  Bs1[bk][be + 6] = b1v.z;  Bs1[bk][be + 7] = b1v.w;
      Bs1[bk][be + 8] = b2v.x;  Bs1[bk][be + 9] = b2v.y;  Bs1[bk][be + 10] = b2v.z; Bs1[bk][be + 11] = b2v.w;
      Bs1[bk][be + 12] = b3v.x; Bs1[bk][be + 13] = b3v.y; Bs1[bk][be + 14] = b3v.z; Bs1[bk][be + 15] = b3v.w;
      __syncthreads();
      #pragma unroll
      for (int kk = 0; kk < 16; kk++) {
        float4 a = *(const float4*)&Sa[kk][t0];
        float4 b = *(const float4*)&Bs1[kk][e0];
        acc[0][0] += a.x * b.x; acc[0][1] += a.x * b.y; acc[0][2] += a.x * b.z; acc[0][3] += a.x * b.w;
        acc[1][0] += a.y * b.x; acc[1][1] += a.y * b.y; acc[1][2] += a.y * b.z; acc[1][3] += a.y * b.w;
        acc[2][0] += a.z * b.x; acc[2][1] += a.z * b.y; acc[2][2] += a.z * b.z; acc[2][3] += a.z * b.w;
        acc[3][0] += a.w * b.x; acc[3][1] += a.w * b.y; acc[3][2] += a.w * b.z; acc[3][3] += a.w * b.w;
      }
      __syncthreads();
    }
    #pragma unroll
    for (int i = 0; i < 4; i++) {
      float4 hv;
      hv.x = fmaxf(acc[i][0] + b1[e0 + 0], 0.0f);
      hv.y = fmaxf(acc[i][1] + b1[e0 + 1], 0.0f);
      hv.z = fmaxf(acc[i][2] + b1[e0 + 2], 0.0f);
      hv.w = fmaxf(acc[i][3] + b1[e0 + 3], 0.0f);
      *(float4*)&hid[t0 + i][e0] = hv;
    }
  }
  __syncthreads();
  // ---- phase 2: out = LN(hid@W2 + b2 + res), micro 2x4 over 16x128 ----
  {
    const int tm = tid >> 5, tn = tid & 31;
    const int t0 = 2 * tm, e0 = 4 * tn;
    const int bk = tid >> 3, be = (tid & 7) * 16;
    float acc[2][4] = {};
    for (int k0 = 0; k0 < 256; k0 += 32) {
      const float* bp = W2 + (size_t)(k0 + bk) * 128 + be;
      float4 b0v = *(const float4*)(bp + 0);
      float4 b1v = *(const float4*)(bp + 4);
      float4 b2v = *(const float4*)(bp + 8);
      float4 b3v = *(const float4*)(bp + 12);
      Bs2[bk][be + 0] = b0v.x;  Bs2[bk][be + 1] = b0v.y;  Bs2[bk][be + 2] = b0v.z;  Bs2[bk][be + 3] = b0v.w;
      Bs2[bk][be + 4] = b1v.x;  Bs2[bk][be + 5] = b1v.y;  Bs2[bk][be + 6] = b1v.z;  Bs2[bk][be + 7] = b1v.w;
      Bs2[bk][be + 8] = b2v.x;  Bs2[bk][be + 9] = b2v.y;  Bs2[bk][be + 10] = b2v.z; Bs2[bk][be + 11] = b2v.w;
      Bs2[bk][be + 12] = b3v.x; Bs2[bk][be + 13] = b3v.y; Bs2[bk][be + 14] = b3v.z; Bs2[bk][be + 15] = b3v.w;
      __syncthreads();
      #pragma unroll
      for (int kk = 0; kk < 32; kk++) {
        float a0 = hid[t0 + 0][k0 + kk];
        float a1 = hid[t0 + 1][k0 + kk];
        float4 b = *(const float4*)&Bs2[kk][e0];
        acc[0][0] += a0 * b.x; acc[0][1] += a0 * b.y; acc[0][2] += a0 * b.z; acc[0][3] += a0 * b.w;
        acc[1][0] += a1 * b.x; acc[1][1] += a1 * b.y; acc[1][2] += a1 * b.z; acc[1][3] += a1 * b.w;
      }
      __syncthreads();
    }
    #pragma unroll
    for (int i = 0; i < 2; i++) {
      int r = row0 + t0 + i;
      float v0 = acc[i][0] + b2[e0 + 0] + res[(size_t)r * 128 + e0 + 0];
      float v1 = acc[i][1] + b2[e0 + 1] + res[(size_t)r * 128 + e0 + 1];
      float v2 = acc[i][2] + b2[e0 + 2] + res[(size_t)r * 128 + e0 + 2];
      float v3 = acc[i][3] + b2[e0 + 3] + res[(size_t)r * 128 + e0 + 3];
      float s = v0 + v1 + v2 + v3;
      #pragma unroll
      for (int o = 1; o < 32; o <<= 1) s += __shfl_xor(s, o);
      float mean = s * (1.0f / 128.0f);
      float d0 = v0 - mean, d1 = v1 - mean, d2 = v2 - mean, d3 = v3 - mean;
      float sq = d0 * d0 + d1 * d1 + d2 * d2 + d3 * d3;
      #pragma unroll
      for (int o = 1; o < 32; o <<= 1) sq += __shfl_xor(sq, o);
      float rstd = 1.0f / sqrtf(sq * (1.0f / 128.0f) + 1e-5f);
      float* cp = C + (size_t)r * 128 + e0;
      cp[0] = d0 * rstd * g[e0 + 0] + bb[e0 + 0];
      cp[1] = d1 * rstd * g[e0 + 1] + bb[e0 + 1];
      cp[2] = d2 * rstd * g[e0 + 2] + bb[e0 + 2];
      cp[3] = d3 * rstd * g[e0 + 3] + bb[e0 + 3];
    }
  }
}

// ---------------------------------------------------------------- LayerNorm rows of 128 (after edge aggr)
__global__ __launch_bounds__(128) void ln_k(
    const float* __restrict__ x, const float* __restrict__ res,
    const float* __restrict__ g, const float* __restrict__ b, float* __restrict__ out)
{
  __shared__ float sred[2];
  int r = blockIdx.x, e = threadIdx.x;
  size_t idx = (size_t)r * 128 + e;
  float v = x[idx] + res[idx];
  float nv = blk_norm(v, e, sred);
  out[idx] = nv * g[e] + b[e];
}

// ---------------------------------------------------------------- graph attention (N=32, GD=16) per (g,h)
__global__ __launch_bounds__(256) void gattn_k(
    const float* __restrict__ q, const float* __restrict__ k, const float* __restrict__ v,
    const float* __restrict__ dist, float* __restrict__ o)
{
  __shared__ float qs[32][17], ksh[32][17], vsh[32][17], ss[32][33], rs[32];
  const int g = blockIdx.x, h = blockIdx.y, tid = threadIdx.x;
  {
    int idx = tid * 2;
    int i = idx >> 4, d = idx & 15;
    size_t base = ((size_t)(g * 32 + i)) * 128 + h * 16 + d;
    qs[i][d] = q[base];  qs[i][d + 1] = q[base + 1];
    ksh[i][d] = k[base]; ksh[i][d + 1] = k[base + 1];
    vsh[i][d] = v[base]; vsh[i][d + 1] = v[base + 1];
  }
  __syncthreads();
  {
    int i = tid >> 3, j0 = (tid & 7) * 4;
    for (int j = j0; j < j0 + 4; j++) {
      float a = 0;
      #pragma unroll
      for (int d = 0; d < 16; d++) a += qs[i][d] * ksh[j][d];
      a = a * 0.25f + dist[(size_t)g * 1024 + i * 32 + j];
      ss[i][j] = fminf(fmaxf(a, -10.0f), 10.0f);
    }
  }
  __syncthreads();
  if (tid < 32) {
    float m = -1e30f;
    for (int j = 0; j < 32; j++) m = fmaxf(m, ss[tid][j]);
    float sm = 0;
    for (int j = 0; j < 32; j++) { float ex = expf(ss[tid][j] - m); ss[tid][j] = ex; sm += ex; }
    rs[tid] = 1.0f / sm;
  }
  __syncthreads();
  {
    int idx = tid * 2;
    int i = idx >> 4, d = idx & 15;
    float a0 = 0, a1 = 0;
    for (int j = 0; j < 32; j++) { float wj = ss[i][j]; a0 += wj * vsh[j][d]; a1 += wj * vsh[j][d + 1]; }
    float r = rs[i];
    size_t base = ((size_t)(g * 32 + i)) * 128 + h * 16 + d;
    o[base] = a0 * r; o[base + 1] = a1 * r;
  }
}

// ---------------------------------------------------------------- sequence attention (L=128, SD=32) per (b,h,qtile)
__global__ __launch_bounds__(256) void sattn_k(const float* __restrict__ qkv, float* __restrict__ o)
{
  __shared__ float ks[128][33];
  __shared__ float vs[128][33];
  __shared__ float qs[32][33];
  __shared__ float ss[32][129];
  __shared__ float red[32][8];
  __shared__ float red2[32][8];
  const int b = blockIdx.x, h = blockIdx.y, qt = blockIdx.z, tid = threadIdx.x;
  {
    int l = tid >> 1, d0 = (tid & 1) * 16;
    const float* kp = qkv + ((size_t)(b * 128 + l)) * 384 + 128 + h * 32 + d0;
    #pragma unroll
    for (int j = 0; j < 16; j++) { ks[l][d0 + j] = kp[j]; vs[l][d0 + j] = kp[128 + j]; }
  }
  {
    int i = tid >> 3, d0 = (tid & 7) * 4;
    const float* qp = qkv + ((size_t)(b * 128 + qt * 32 + i)) * 384 + h * 32 + d0;
    #pragma unroll
    for (int j = 0; j < 4; j++) qs[i][d0 + j] = qp[j];
  }
  __syncthreads();
  const int i = tid >> 3, sub = tid & 7;
  {
    int j0 = sub * 16;
    for (int j = j0; j < j0 + 16; j++) {
      float a = 0;
      #pragma unroll
      for (int d = 0; d < 32; d++) a += qs[i][d] * ks[j][d];
      ss[i][j] = a * 0.17677669529663687f;
    }
  }
  __syncthreads();
  float m = -1e30f;
  for (int j = sub; j < 128; j += 8) m = fmaxf(m, ss[i][j]);
  red[i][sub] = m;
  __syncthreads();
  float mm = red[i][0];
  #pragma unroll
  for (int t = 1; t < 8; t++) mm = fmaxf(mm, red[i][t]);
  float ps = 0;
  for (int j = sub; j < 128; j += 8) { float ex = expf(ss[i][j] - mm); ss[i][j] = ex; ps += ex; }
  red2[i][sub] = ps;
  __syncthreads();
  float sm = 0;
  #pragma unroll
  for (int t = 0; t < 8; t++) sm += red2[i][t];
  float rinv = 1.0f / sm;
  {
    int d0 = sub * 4;
    float a0 = 0, a1 = 0, a2 = 0, a3 = 0;
    for (int j = 0; j < 128; j++) {
      float wj = ss[i][j];
      a0 += wj * vs[j][d0 + 0]; a1 += wj * vs[j][d0 + 1];
      a2 += wj * vs[j][d0 + 2]; a3 += wj * vs[j][d0 + 3];
    }
    float* op = o + ((size_t)(b * 128 + qt * 32 + i)) * 128 + h * 32 + d0;
    op[0] = a0 * rinv; op[1] = a1 * rinv; op[2] = a2 * rinv; op[3] = a3 * rinv;
  }
}

// ---------------------------------------------------------------- embedding
__global__ __launch_bounds__(128) void embed_k(
    const int* __restrict__ tokens, const float* __restrict__ tok_emb,
    const float* __restrict__ pos_emb, float* __restrict__ xs)
{
  int r = blockIdx.x, e = threadIdx.x;
  int tk = tokens[r];
  xs[(size_t)r * 128 + e] = tok_emb[(size_t)tk * 128 + e] + pos_emb[(size_t)(r & 127) * 128 + e];
}

// ---------------------------------------------------------------- pool + smean + fusion + cross-modal + head
__global__ __launch_bounds__(128) void head_k(
    const float* __restrict__ hb, const float* __restrict__ xs, const float* __restrict__ gfeat,
    const float* fg1w, const float* fg1b, const float* fg2w, const float* fg2b,
    const float* g2s_vw, const float* g2s_vb, const float* g2s_ow, const float* g2s_ob,
    const float* n1g, const float* n1b,
    const float* s2g_vw, const float* s2g_vb, const float* s2g_ow, const float* s2g_ob,
    const float* n2g, const float* n2b,
    const float* r1w, const float* r1b, const float* r2w, const float* r2b,
    float* __restrict__ out)
{
  __shared__ float T[128], S[128], G[128], Sm[128], t1[128], t2[128], gh[64], sred[2];
  int mol = blockIdx.x, e = threadIdx.x;
  {
    float cs = 0;
    for (int c = 0; c < 4; c++) {
      int g = mol * 4 + c;
      float s = 0;
      for (int i = 0; i < 32; i++) s += hb[((size_t)(g * 32 + i)) * 128 + e];
      cs += s * (1.0f / 32.0f);
    }
    cs *= 0.25f;
    float s2 = 0;
    int g = 64 + mol;
    for (int i = 0; i < 32; i++) s2 += hb[((size_t)(g * 32 + i)) * 128 + e];
    T[e] = cs + s2 * (1.0f / 32.0f);
    float ss = 0;
    for (int l = 0; l < 128; l++) ss += xs[((size_t)(mol * 128 + l)) * 128 + e];
    S[e] = ss * (1.0f / 128.0f);
  }
  __syncthreads();
  if (e < 64) {
    float a = fg1b[e];
    for (int f = 0; f < 128; f++) a += T[f] * fg1w[f * 64 + e];
    for (int f = 0; f < 128; f++) a += S[f] * fg1w[(128 + f) * 64 + e];
    gh[e] = fmaxf(a, 0.0f);
  }
  __syncthreads();
  {
    float a = fg2b[e];
    for (int j = 0; j < 64; j++) a += gh[j] * fg2w[j * 128 + e];
    float gate = 1.0f / (1.0f + expf(-a));
    float fu = gate * T[e] + (1.0f - gate) * S[e];
    G[e] = fu; Sm[e] = fu;
  }
  __syncthreads();
  for (int l = 0; l < 2; l++) {
    const float* vw = g2s_vw + (size_t)l * 16384; const float* vb = g2s_vb + l * 128;
    const float* ow = g2s_ow + (size_t)l * 16384; const float* ob = g2s_ob + l * 128;
    float a = vb[e];
    for (int f = 0; f < 128; f++) a += Sm[f] * vw[f * 128 + e];
    t1[e] = a;
    __syncthreads();
    a = ob[e];
    for (int f = 0; f < 128; f++) a += t1[f] * ow[f * 128 + e];
    float nv = blk_norm(G[e] + a, e, sred);
    G[e] = nv * n1g[l * 128 + e] + n1b[l * 128 + e];
    __syncthreads();
    const float* vw2 = s2g_vw + (size_t)l * 16384; const float* vb2 = s2g_vb + l * 128;
    const float* ow2 = s2g_ow + (size_t)l * 16384; const float* ob2 = s2g_ob + l * 128;
    a = vb2[e];
    for (int f = 0; f < 128; f++) a += G[f] * vw2[f * 128 + e];
    t1[e] = a;
    __syncthreads();
    a = ob2[e];
    for (int f = 0; f < 128; f++) a += t1[f] * ow2[f * 128 + e];
    nv = blk_norm(Sm[e] + a, e, sred);
    Sm[e] = nv * n2g[l * 128 + e] + n2b[l * 128 + e];
    __syncthreads();
  }
  t2[e] = 0.5f * (G[e] + Sm[e]);
  __syncthreads();
  float a = r1b[e];
  for (int f = 0; f < 128; f++) a += t2[f] * r1w[f * 128 + e];
  for (int f = 0; f < 3; f++) a += gfeat[mol * 3 + f] * r1w[(128 + f) * 128 + e];
  a = fmaxf(a, 0.0f);
  float p = a * r2w[e];
  #pragma unroll
  for (int o = 1; o < 64; o <<= 1) p += __shfl_xor(p, o);
  if ((e & 63) == 0) sred[e >> 6] = p;
  __syncthreads();
  if (e == 0) out[mol] = sred[0] + sred[1] + r2b[0];
}

// ================================================================ host
extern "C" void kernel_launch(void* const* d_in, const int* in_sizes, int n_in,
                              void* d_out, int out_size, void* d_ws, size_t ws_size,
                              hipStream_t stream)
{
  (void)n_in; (void)out_size; (void)ws_size;
  const bool dict = (in_sizes[1] == 8192);
  auto IN = [&](int di, int si) { return d_in[dict ? di : si]; };

  const float* conf_x   = (const float*)IN(0, 0);
  const int*   conf_ei  = (const int*)  IN(1, 63);
  const float* conf_ea  = (const float*)IN(2, 1);
  const float* conf_pos = (const float*)IN(3, 2);
  const float* scaf_x   = (const float*)IN(4, 3);
  const int*   scaf_ei  = (const int*)  IN(5, 64);
  const float* scaf_ea  = (const float*)IN(6, 4);
  const float* scaf_pos = (const float*)IN(7, 5);
  const int*   tokens   = (const int*)  IN(8, 65);
  const float* gfeat    = (const float*)IN(9, 6);
  const float* gproj_w  = (const float*)IN(11, 7);
  const float* gproj_b  = (const float*)IN(12, 8);
  const float* elin_w   = (const float*)IN(13, 9);
  const float* elin_b   = (const float*)IN(14, 10);
  const float* eln_g    = (const float*)IN(15, 11);
  const float* eln_b    = (const float*)IN(16, 12);
  const float* gt_qw    = (const float*)IN(17, 13);
  const float* gt_qb    = (const float*)IN(18, 14);
  const float* gt_kw    = (const float*)IN(19, 15);
  const float* gt_kb    = (const float*)IN(20, 16);
  const float* gt_vw    = (const float*)IN(21, 17);
  const float* gt_vb    = (const float*)IN(22, 18);
  const float* gt_ow    = (const float*)IN(23, 19);
  const float* gt_ob    = (const float*)IN(24, 20);
  const float* gt_ln1g  = (const float*)IN(25, 21);
  const float* gt_ln1b  = (const float*)IN(26, 22);
  const float* gt_f1w   = (const float*)IN(27, 23);
  const float* gt_f1b   = (const float*)IN(28, 24);
  const float* gt_f2w   = (const float*)IN(29, 25);
  const float* gt_f2b   = (const float*)IN(30, 26);
  const float* gt_ln2g  = (const float*)IN(31, 27);
  const float* gt_ln2b  = (const float*)IN(32, 28);
  const float* tok_emb  = (const float*)IN(33, 29);
  const float* pos_emb  = (const float*)IN(34, 30);
  const float* se_inw   = (const float*)IN(35, 31);
  const float* se_inb   = (const float*)IN(36, 32);
  const float* se_ow    = (const float*)IN(37, 33);
  const float* se_ob    = (const float*)IN(38, 34);
  const float* se_ln1g  = (const float*)IN(39, 35);
  const float* se_ln1b  = (const float*)IN(40, 36);
  const float* se_f1w   = (const float*)IN(41, 37);
  const float* se_f1b   = (const float*)IN(42, 38);
  const float* se_f2w   = (const float*)IN(43, 39);
  const float* se_f2b   = (const float*)IN(44, 40);
  const float* se_ln2g  = (const float*)IN(45, 41);
  const float* se_ln2b  = (const float*)IN(46, 42);
  const float* fg1_w    = (const float*)IN(47, 43);
  const float* fg1_b    = (const float*)IN(48, 44);
  const float* fg2_w    = (const float*)IN(49, 45);
  const float* fg2_b    = (const float*)IN(50, 46);
  const float* cm_g2s_vw = (const float*)IN(51, 47);
  const float* cm_g2s_vb = (const float*)IN(52, 48);
  const float* cm_g2s_ow = (const float*)IN(53, 49);
  const float* cm_g2s_ob = (const float*)IN(54, 50);
  const float* cm_s2g_vw = (const float*)IN(55, 53);
  const float* cm_s2g_vb = (const float*)IN(56, 54);
  const float* cm_s2g_ow = (const float*)IN(57, 55);
  const float* cm_s2g_ob = (const float*)IN(58, 56);
  const float* cm_n1g   = (const float*)IN(59, 51);
  const float* cm_n1b   = (const float*)IN(60, 52);
  const float* cm_n2g   = (const float*)IN(61, 57);
  const float* cm_n2b   = (const float*)IN(62, 58);
  const float* r1_w     = (const float*)IN(63, 59);
  const float* r1_b     = (const float*)IN(64, 60);
  const float* r2_w     = (const float*)IN(65, 61);
  const float* r2_b     = (const float*)IN(66, 62);
  float* out = (float*)d_out;

  // ---- workspace (fp32) ----
  float* w = (float*)d_ws;
  size_t off = 0;
  auto alloc = [&](size_t n) { float* p = w + off; off += n; return p; };
  float* h     = alloc(2560 * 128);
  float* aggr  = alloc(2560 * 128);
  float* hb    = alloc(2560 * 128);
  float* distb = alloc(80 * 1024);
  float* gtmp  = alloc(2949120);
  float* xsfin = alloc(2048 * 128);
  // graph carve
  float* qb    = gtmp;                  // q/k/v contiguous, stride 327680
  float* atto  = gtmp + 983040;
  float* x1b   = gtmp + 1310720;
  // seq carve
  float* xs2    = gtmp;                 // 2048*128
  float* qkv3   = gtmp + 262144;        // 2048*384
  float* satto  = gtmp + 1048576;
  float* sx1    = gtmp + 1310720;

  // ============ graph encoder ============
  node_proj_k<<<2560, 128, 0, stream>>>(conf_x, scaf_x, gproj_w, gproj_b, h, aggr);
  dist_k<<<80, 256, 0, stream>>>(conf_pos, scaf_pos, distb);
  edge_gemm_k<<<dim3(160, 14), 256, 0, stream>>>(conf_ea, scaf_ea, conf_ei, scaf_ei, h, elin_w, elin_b, aggr);
  ln_k<<<2560, 128, 0, stream>>>(aggr, h, eln_g, eln_b, hb);

  for (int l = 0; l < 3; l++) {
    gemm3_k<<<dim3(3, 160), 256, 0, stream>>>(hb,
        gt_qw + (size_t)l * 16384, gt_kw + (size_t)l * 16384, gt_vw + (size_t)l * 16384,
        gt_qb + l * 128, gt_kb + l * 128, gt_vb + l * 128, qb, 327680);
    gattn_k<<<dim3(80, 8), 256, 0, stream>>>(qb, qb + 327680, qb + 655360, distb, atto);
    gemm_ln_k<<<160, 256, 0, stream>>>(atto, gt_ow + (size_t)l * 16384, gt_ob + l * 128,
                                       hb, gt_ln1g + l * 128, gt_ln1b + l * 128, x1b, 128);
    ffn_k<<<160, 256, 0, stream>>>(x1b, gt_f1w + (size_t)l * 32768, gt_f1b + l * 256,
                                   gt_f2w + (size_t)l * 32768, gt_f2b + l * 128,
                                   x1b, gt_ln2g + l * 128, gt_ln2b + l * 128, hb);
  }

  // ============ sequence encoder ============
  embed_k<<<2048, 128, 0, stream>>>(tokens, tok_emb, pos_emb, xs2);
  for (int l = 0; l < 4; l++) {
    gemm16_k<<<dim3(3, 128), 256, 0, stream>>>(xs2, se_inw + (size_t)l * 49152, se_inb + l * 384, qkv3, 128, 384);
    sattn_k<<<dim3(16, 4, 4), 256, 0, stream>>>(qkv3, satto);
    gemm_ln_k<<<128, 256, 0, stream>>>(satto, se_ow + (size_t)l * 16384, se_ob + l * 128,
                                       xs2, se_ln1g + l * 128, se_ln1b + l * 128, sx1, 128);
    ffn_k<<<128, 256, 0, stream>>>(sx1, se_f1w + (size_t)l * 32768, se_f1b + l * 256,
                                   se_f2w + (size_t)l * 32768, se_f2b + l * 128,
                                   sx1, se_ln2g + l * 128, se_ln2b + l * 128,
                                   (l == 3) ? xsfin : xs2);
  }

  // ============ pool + smean + fusion + cross-modal + regressor ============
  head_k<<<16, 128, 0, stream>>>(hb, xsfin, gfeat,
                                 fg1_w, fg1_b, fg2_w, fg2_b,
                                 cm_g2s_vw, cm_g2s_vb, cm_g2s_ow, cm_g2s_ob, cm_n1g, cm_n1b,
                                 cm_s2g_vw, cm_s2g_vb, cm_s2g_ow, cm_s2g_ob, cm_n2g, cm_n2b,
                                 r1_w, r1_b, r2_w, r2_b, out);
}